// Round 5
// baseline (391.057 us; speedup 1.0000x reference)
//
#include <hip/hip_runtime.h>
#include <hip/hip_bf16.h>

#define DD 96

// ---------------- dtype detect ----------------
__global__ void detect_idx_kernel(const unsigned long long* __restrict__ idx,
                                  int* __restrict__ flag,
                                  unsigned long long nmax) {
    __shared__ int bad;
    if (threadIdx.x == 0) bad = 0;
    __syncthreads();
    unsigned long long v = idx[threadIdx.x];
    if (v >= nmax) bad = 1;
    __syncthreads();
    if (threadIdx.x == 0) *flag = bad ? 0 : 1;  // 1 => int64 layout
}

__device__ __forceinline__ int load_idx(const void* eidx, int isI64, int pos) {
    return isI64 ? (int)((const long long*)eidx)[pos] : ((const int*)eidx)[pos];
}

// ---------------- CSR build ----------------
__global__ __launch_bounds__(256) void hist_kernel(
    const void* __restrict__ eidx, const int* __restrict__ flag,
    int* __restrict__ deg, int E, int n) {
    int e0 = (blockIdx.x * 256 + threadIdx.x) * 4;
    if (e0 >= E) return;
    const int isI64 = *flag;
    if (e0 + 4 <= E) {
        int d0 = load_idx(eidx, isI64, E + e0 + 0);
        int d1 = load_idx(eidx, isI64, E + e0 + 1);
        int d2 = load_idx(eidx, isI64, E + e0 + 2);
        int d3 = load_idx(eidx, isI64, E + e0 + 3);
        if ((unsigned)d0 < (unsigned)n) atomicAdd(&deg[d0], 1);
        if ((unsigned)d1 < (unsigned)n) atomicAdd(&deg[d1], 1);
        if ((unsigned)d2 < (unsigned)n) atomicAdd(&deg[d2], 1);
        if ((unsigned)d3 < (unsigned)n) atomicAdd(&deg[d3], 1);
    } else {
        for (int e = e0; e < E; ++e) {
            int d = load_idx(eidx, isI64, E + e);
            if ((unsigned)d < (unsigned)n) atomicAdd(&deg[d], 1);
        }
    }
}

#define SCAN_BLOCK 256
#define SCAN_ELEMS 1024

__global__ __launch_bounds__(SCAN_BLOCK) void scan1_kernel(
    const int* __restrict__ deg, int* __restrict__ partial,
    int* __restrict__ blockSums, int n) {
    __shared__ int sh[SCAN_BLOCK];
    int base = blockIdx.x * SCAN_ELEMS;
    int vals[4];
    int tsum = 0;
    #pragma unroll
    for (int u = 0; u < 4; ++u) {
        int idx = base + threadIdx.x * 4 + u;
        vals[u] = (idx < n) ? deg[idx] : 0;
        tsum += vals[u];
    }
    sh[threadIdx.x] = tsum;
    __syncthreads();
    int v = tsum;
    for (int off = 1; off < SCAN_BLOCK; off <<= 1) {
        int o = (threadIdx.x >= off) ? sh[threadIdx.x - off] : 0;
        __syncthreads();
        v += o;
        sh[threadIdx.x] = v;
        __syncthreads();
    }
    int run = v - tsum;
    #pragma unroll
    for (int u = 0; u < 4; ++u) {
        int idx = base + threadIdx.x * 4 + u;
        if (idx < n) partial[idx] = run;
        run += vals[u];
    }
    if (threadIdx.x == SCAN_BLOCK - 1) blockSums[blockIdx.x] = v;
}

__global__ __launch_bounds__(256) void scan2_kernel(int* __restrict__ blockSums, int nb) {
    __shared__ int sh[256];
    int v = (threadIdx.x < nb) ? blockSums[threadIdx.x] : 0;
    sh[threadIdx.x] = v;
    __syncthreads();
    int inc = v;
    for (int off = 1; off < 256; off <<= 1) {
        int o = (threadIdx.x >= off) ? sh[threadIdx.x - off] : 0;
        __syncthreads();
        inc += o;
        sh[threadIdx.x] = inc;
        __syncthreads();
    }
    if (threadIdx.x < nb) blockSums[threadIdx.x] = inc - v;
}

__global__ __launch_bounds__(256) void scan3_kernel(
    const int* __restrict__ partial, const int* __restrict__ blockSums,
    int* __restrict__ offsets, int* __restrict__ cursor, int n, int E) {
    int i = blockIdx.x * 256 + threadIdx.x;
    if (i < n) {
        int o = partial[i] + blockSums[i >> 10];
        offsets[i] = o;
        cursor[i] = o;
    }
    if (i == n) offsets[n] = E;
}

__global__ __launch_bounds__(256) void bucket_kernel(
    const void* __restrict__ eidx, const int* __restrict__ flag,
    int* __restrict__ cursor, int* __restrict__ ssrc, int E, int n) {
    int e0 = (blockIdx.x * 256 + threadIdx.x) * 4;
    if (e0 >= E) return;
    const int isI64 = *flag;
    if (e0 + 4 <= E) {
        int s0 = load_idx(eidx, isI64, e0 + 0);
        int s1 = load_idx(eidx, isI64, e0 + 1);
        int s2 = load_idx(eidx, isI64, e0 + 2);
        int s3 = load_idx(eidx, isI64, e0 + 3);
        int d0 = load_idx(eidx, isI64, E + e0 + 0);
        int d1 = load_idx(eidx, isI64, E + e0 + 1);
        int d2 = load_idx(eidx, isI64, E + e0 + 2);
        int d3 = load_idx(eidx, isI64, E + e0 + 3);
        bool v0 = (unsigned)s0 < (unsigned)n && (unsigned)d0 < (unsigned)n;
        bool v1 = (unsigned)s1 < (unsigned)n && (unsigned)d1 < (unsigned)n;
        bool v2 = (unsigned)s2 < (unsigned)n && (unsigned)d2 < (unsigned)n;
        bool v3 = (unsigned)s3 < (unsigned)n && (unsigned)d3 < (unsigned)n;
        int p0 = v0 ? atomicAdd(&cursor[d0], 1) : 0;
        int p1 = v1 ? atomicAdd(&cursor[d1], 1) : 0;
        int p2 = v2 ? atomicAdd(&cursor[d2], 1) : 0;
        int p3 = v3 ? atomicAdd(&cursor[d3], 1) : 0;
        if (v0) ssrc[p0] = s0;
        if (v1) ssrc[p1] = s1;
        if (v2) ssrc[p2] = s2;
        if (v3) ssrc[p3] = s3;
    } else {
        for (int e = e0; e < E; ++e) {
            int s = load_idx(eidx, isI64, e);
            int d = load_idx(eidx, isI64, E + e);
            if ((unsigned)s >= (unsigned)n || (unsigned)d >= (unsigned)n) continue;
            int pos = atomicAdd(&cursor[d], 1);
            ssrc[pos] = s;
        }
    }
}

// ---------------- gather aggregation (no atomics) ----------------
__global__ __launch_bounds__(256) void gather_agg_kernel(
    const float* __restrict__ feat, const int* __restrict__ offsets,
    const int* __restrict__ ssrc, float* __restrict__ agg, int n) {
    long long t = (long long)blockIdx.x * 256 + threadIdx.x;
    if (t >= (long long)n * 24) return;
    int i = (int)(t / 24);
    int c = (int)(t % 24);
    int beg = offsets[i], end = offsets[i + 1];
    float4 accA = make_float4(0.f, 0.f, 0.f, 0.f);
    float4 accB = make_float4(0.f, 0.f, 0.f, 0.f);
    int j = beg;
    for (; j + 4 <= end; j += 4) {
        int s0 = ssrc[j + 0];
        int s1 = ssrc[j + 1];
        int s2 = ssrc[j + 2];
        int s3 = ssrc[j + 3];
        float4 v0 = ((const float4*)(feat + (size_t)s0 * DD))[c];
        float4 v1 = ((const float4*)(feat + (size_t)s1 * DD))[c];
        float4 v2 = ((const float4*)(feat + (size_t)s2 * DD))[c];
        float4 v3 = ((const float4*)(feat + (size_t)s3 * DD))[c];
        accA.x += v0.x; accA.y += v0.y; accA.z += v0.z; accA.w += v0.w;
        accB.x += v1.x; accB.y += v1.y; accB.z += v1.z; accB.w += v1.w;
        accA.x += v2.x; accA.y += v2.y; accA.z += v2.z; accA.w += v2.w;
        accB.x += v3.x; accB.y += v3.y; accB.z += v3.z; accB.w += v3.w;
    }
    for (; j < end; ++j) {
        int s = ssrc[j];
        float4 v = ((const float4*)(feat + (size_t)s * DD))[c];
        accA.x += v.x; accA.y += v.y; accA.z += v.z; accA.w += v.w;
    }
    accA.x += accB.x; accA.y += accB.y; accA.z += accB.z; accA.w += accB.w;
    ((float4*)(agg + (size_t)i * DD))[c] = accA;
}

// ---------------- fallback: atomic scatter ----------------
__global__ __launch_bounds__(256) void scatter_add_kernel(
    const float* __restrict__ feat, const void* __restrict__ eidx,
    const int* __restrict__ flag, float* __restrict__ agg,
    int E, int n) {
    long long t = (long long)blockIdx.x * 256 + threadIdx.x;
    if (t >= (long long)E * 24) return;
    int e = (int)(t / 24);
    int c = (int)(t % 24);
    int isI64 = *flag;
    int s = load_idx(eidx, isI64, e);
    int d = load_idx(eidx, isI64, E + e);
    if ((unsigned)s >= (unsigned)n || (unsigned)d >= (unsigned)n) return;
    const float4 v = ((const float4*)(feat + (size_t)s * DD))[c];
    float* o = agg + (size_t)d * DD + (size_t)c * 4;
    atomicAdd(o + 0, v.x);
    atomicAdd(o + 1, v.y);
    atomicAdd(o + 2, v.z);
    atomicAdd(o + 3, v.w);
}

// ---------------- fast dual-linear: column-slab blocks ----------------
// Block = 256 threads = 256 nodes, blockIdx.y = col-quarter q (24 cols).
// LDS: 96x24 slabs of Wrel and Wroot (18.4 KB) -> 8 blocks/CU, grid 196x4.
// REQUIRES out disjoint from A and X (no in-place).
__global__ __launch_bounds__(256, 6) void linear_cols_kernel(
    const float* __restrict__ A, const float* __restrict__ X,
    const float* __restrict__ Wrel, const float* __restrict__ bias,
    const float* __restrict__ Wroot, float* __restrict__ out,
    int n, int do_relu) {
    __shared__ float wr_s[DD * 24];  // 9216 B
    __shared__ float wo_s[DD * 24];  // 9216 B

    const int q = blockIdx.y;        // 0..3
    const int j0 = q * 24;
    const int node = blockIdx.x * 256 + threadIdx.x;
    const bool act = (node < n);
    const int r = act ? node : 0;

    // stage W slabs: 576 float4 per matrix; row k cols j0..j0+23
    for (int idx = threadIdx.x; idx < DD * 6; idx += 256) {
        int k = idx / 6, c = idx % 6;
        ((float4*)wr_s)[idx] = ((const float4*)(Wrel  + (size_t)k * DD + j0))[c];
        ((float4*)wo_s)[idx] = ((const float4*)(Wroot + (size_t)k * DD + j0))[c];
    }
    __syncthreads();

    float acc[24];
    {
        const float4* bq = (const float4*)(bias + j0);
        #pragma unroll
        for (int jj = 0; jj < 6; ++jj) {
            float4 b = bq[jj];
            acc[jj*4+0] = b.x; acc[jj*4+1] = b.y;
            acc[jj*4+2] = b.z; acc[jj*4+3] = b.w;
        }
    }

    const float4* arow = (const float4*)(A + (size_t)r * DD);
    const float4* xrow = (const float4*)(X + (size_t)r * DD);

    for (int kc = 0; kc < DD / 4; ++kc) {
        float4 a4 = arow[kc];
        float4 x4 = xrow[kc];
        const float av[4] = {a4.x, a4.y, a4.z, a4.w};
        const float xv[4] = {x4.x, x4.y, x4.z, x4.w};
        #pragma unroll
        for (int u = 0; u < 4; ++u) {
            const float4* wr = (const float4*)(&wr_s[(kc * 4 + u) * 24]);
            const float4* wo = (const float4*)(&wo_s[(kc * 4 + u) * 24]);
            const float ka = av[u], kx = xv[u];
            #pragma unroll
            for (int jj = 0; jj < 6; ++jj) {
                float4 w1 = wr[jj];
                float4 w2 = wo[jj];
                acc[jj*4+0] = fmaf(ka, w1.x, fmaf(kx, w2.x, acc[jj*4+0]));
                acc[jj*4+1] = fmaf(ka, w1.y, fmaf(kx, w2.y, acc[jj*4+1]));
                acc[jj*4+2] = fmaf(ka, w1.z, fmaf(kx, w2.z, acc[jj*4+2]));
                acc[jj*4+3] = fmaf(ka, w1.w, fmaf(kx, w2.w, acc[jj*4+3]));
            }
        }
    }

    if (act) {
        float4* o = (float4*)(out + (size_t)node * DD + j0);
        #pragma unroll
        for (int jj = 0; jj < 6; ++jj) {
            float4 v = make_float4(acc[jj*4+0], acc[jj*4+1],
                                   acc[jj*4+2], acc[jj*4+3]);
            if (do_relu) {
                v.x = fmaxf(v.x, 0.f); v.y = fmaxf(v.y, 0.f);
                v.z = fmaxf(v.z, 0.f); v.w = fmaxf(v.w, 0.f);
            }
            o[jj] = v;
        }
    }
}

// ---------------- alias-safe dual-linear (layer-2 fallback) ----------------
// Block covers its own 128 rows only; barrier before stores => X may alias out.
__global__ __launch_bounds__(256) void linear_kernel(
    const float* __restrict__ A, const float* __restrict__ X,
    const float* __restrict__ Wrel, const float* __restrict__ bias,
    const float* __restrict__ Wroot, float* __restrict__ out,
    int n, int do_relu) {
    __shared__ float wlds[DD * DD];  // 36864 B

    const int lane = threadIdx.x & 63;
    const int q = threadIdx.x >> 6;
    const int j0 = q * 24;
    const int m0 = blockIdx.x * 128 + lane;
    const int m1 = m0 + 64;
    const bool act0 = (m0 < n), act1 = (m1 < n);
    const int r0 = act0 ? m0 : 0;
    const int r1 = act1 ? m1 : 0;

    float acc0[24], acc1[24];
    {
        const float4* bq = (const float4*)(bias + j0);
        #pragma unroll
        for (int jj = 0; jj < 6; ++jj) {
            float4 b = bq[jj];
            acc0[jj*4+0] = b.x; acc0[jj*4+1] = b.y;
            acc0[jj*4+2] = b.z; acc0[jj*4+3] = b.w;
            acc1[jj*4+0] = b.x; acc1[jj*4+1] = b.y;
            acc1[jj*4+2] = b.z; acc1[jj*4+3] = b.w;
        }
    }

    const float* srcs[2] = {A, X};
    const float* mats[2] = {Wrel, Wroot};

    for (int phase = 0; phase < 2; ++phase) {
        {
            const float4* wg = (const float4*)mats[phase];
            float4* wl = (float4*)wlds;
            #pragma unroll
            for (int i = 0; i < 9; ++i)
                wl[threadIdx.x + i * 256] = wg[threadIdx.x + i * 256];
        }
        __syncthreads();

        const float* row0 = srcs[phase] + (size_t)r0 * DD;
        const float* row1 = srcs[phase] + (size_t)r1 * DD;

        for (int kk = 0; kk < DD; kk += 4) {
            float4 a0 = *(const float4*)(row0 + kk);
            float4 a1 = *(const float4*)(row1 + kk);
            const float av0[4] = {a0.x, a0.y, a0.z, a0.w};
            const float av1[4] = {a1.x, a1.y, a1.z, a1.w};
            #pragma unroll
            for (int u = 0; u < 4; ++u) {
                const float4* wrow = (const float4*)(&wlds[(kk + u) * DD + j0]);
                const float k0 = av0[u], k1 = av1[u];
                #pragma unroll
                for (int jj = 0; jj < 6; ++jj) {
                    float4 w = wrow[jj];
                    acc0[jj*4+0] = fmaf(k0, w.x, acc0[jj*4+0]);
                    acc0[jj*4+1] = fmaf(k0, w.y, acc0[jj*4+1]);
                    acc0[jj*4+2] = fmaf(k0, w.z, acc0[jj*4+2]);
                    acc0[jj*4+3] = fmaf(k0, w.w, acc0[jj*4+3]);
                    acc1[jj*4+0] = fmaf(k1, w.x, acc1[jj*4+0]);
                    acc1[jj*4+1] = fmaf(k1, w.y, acc1[jj*4+1]);
                    acc1[jj*4+2] = fmaf(k1, w.z, acc1[jj*4+2]);
                    acc1[jj*4+3] = fmaf(k1, w.w, acc1[jj*4+3]);
                }
            }
        }
        __syncthreads();
    }

    if (act0) {
        float4* o = (float4*)(out + (size_t)m0 * DD + j0);
        #pragma unroll
        for (int jj = 0; jj < 6; ++jj) {
            float4 v = make_float4(acc0[jj*4+0], acc0[jj*4+1],
                                   acc0[jj*4+2], acc0[jj*4+3]);
            if (do_relu) {
                v.x = fmaxf(v.x, 0.f); v.y = fmaxf(v.y, 0.f);
                v.z = fmaxf(v.z, 0.f); v.w = fmaxf(v.w, 0.f);
            }
            o[jj] = v;
        }
    }
    if (act1) {
        float4* o = (float4*)(out + (size_t)m1 * DD + j0);
        #pragma unroll
        for (int jj = 0; jj < 6; ++jj) {
            float4 v = make_float4(acc1[jj*4+0], acc1[jj*4+1],
                                   acc1[jj*4+2], acc1[jj*4+3]);
            if (do_relu) {
                v.x = fmaxf(v.x, 0.f); v.y = fmaxf(v.y, 0.f);
                v.z = fmaxf(v.z, 0.f); v.w = fmaxf(v.w, 0.f);
            }
            o[jj] = v;
        }
    }
}

extern "C" void kernel_launch(void* const* d_in, const int* in_sizes, int n_in,
                              void* d_out, int out_size, void* d_ws, size_t ws_size,
                              hipStream_t stream) {
    const float* x      = (const float*)d_in[0];
    const void*  eidx   = d_in[1];
    const float* W1_rel = (const float*)d_in[2];
    const float* b1     = (const float*)d_in[3];
    const float* W1_root= (const float*)d_in[4];
    const float* W2_rel = (const float*)d_in[5];
    const float* b2     = (const float*)d_in[6];
    const float* W2_root= (const float*)d_in[7];
    float* out = (float*)d_out;

    const int N = in_sizes[0] / DD;   // 50000
    const int E = in_sizes[1] / 2;    // 800000

    const size_t aggB = (size_t)N * DD * sizeof(float);
    char* base = (char*)d_ws;
    float* agg  = (float*)base;
    int*   flag = (int*)(base + aggB);
    size_t off = (aggB + 15) & ~(size_t)15;
    off += 16;
    int* offsets   = (int*)(base + off); off += (size_t)(N + 1) * 4;
    int* cursor    = (int*)(base + off); off += (size_t)N * 4;
    int* deg       = (int*)(base + off); off += (size_t)N * 4;
    int* partial   = (int*)(base + off); off += (size_t)N * 4;
    int* blockSums = (int*)(base + off); off += 256 * 4;
    int* ssrc      = (int*)(base + off); off += (size_t)E * 4;
    const bool csr_ok = (off <= ws_size) && (N <= SCAN_ELEMS * 256);
    off = (off + 15) & ~(size_t)15;
    float* hbuf = (float*)(base + off); off += aggB;
    const bool h_ok = (off <= ws_size);   // room for layer-1 output in ws?

    const int linear_blocks = (N + 127) / 128;
    const int edge_blocks4 = (E + 1023) / 1024;
    dim3 lin_grid((N + 255) / 256, 4);

    detect_idx_kernel<<<1, 256, 0, stream>>>(
        (const unsigned long long*)eidx, flag, (unsigned long long)N);

    if (csr_ok) {
        const int NB = (N + SCAN_ELEMS - 1) / SCAN_ELEMS;
        const int gather_blocks = (int)(((long long)N * 24 + 255) / 256);

        hipMemsetAsync(deg, 0, (size_t)N * 4, stream);
        hist_kernel<<<edge_blocks4, 256, 0, stream>>>(eidx, flag, deg, E, N);
        scan1_kernel<<<NB, SCAN_BLOCK, 0, stream>>>(deg, partial, blockSums, N);
        scan2_kernel<<<1, 256, 0, stream>>>(blockSums, NB);
        scan3_kernel<<<(N + 256) / 256, 256, 0, stream>>>(partial, blockSums,
                                                          offsets, cursor, N, E);
        bucket_kernel<<<edge_blocks4, 256, 0, stream>>>(eidx, flag, cursor, ssrc, E, N);

        float* h = h_ok ? hbuf : out;

        // Layer 1: sources agg(ws) + x(input), dest h — always disjoint.
        gather_agg_kernel<<<gather_blocks, 256, 0, stream>>>(x, offsets, ssrc, agg, N);
        linear_cols_kernel<<<lin_grid, 256, 0, stream>>>(agg, x, W1_rel, b1, W1_root,
                                                         h, N, 1);
        // Layer 2
        gather_agg_kernel<<<gather_blocks, 256, 0, stream>>>(h, offsets, ssrc, agg, N);
        if (h_ok) {
            // sources agg(ws) + h(ws), dest d_out — disjoint, fast kernel ok
            linear_cols_kernel<<<lin_grid, 256, 0, stream>>>(agg, h, W2_rel, b2,
                                                             W2_root, out, N, 0);
        } else {
            // h aliases out: use barrier kernel
            linear_kernel<<<linear_blocks, 256, 0, stream>>>(agg, h, W2_rel, b2,
                                                             W2_root, out, N, 0);
        }
    } else {
        const int scatter_blocks = (int)(((long long)E * 24 + 255) / 256);
        hipMemsetAsync(agg, 0, aggB, stream);
        scatter_add_kernel<<<scatter_blocks, 256, 0, stream>>>(x, eidx, flag, agg, E, N);
        linear_cols_kernel<<<lin_grid, 256, 0, stream>>>(agg, x, W1_rel, b1, W1_root,
                                                         out, N, 1);
        hipMemsetAsync(agg, 0, aggB, stream);
        scatter_add_kernel<<<scatter_blocks, 256, 0, stream>>>(out, eidx, flag, agg, E, N);
        linear_kernel<<<linear_blocks, 256, 0, stream>>>(agg, out, W2_rel, b2, W2_root,
                                                         out, N, 0);
    }
}

// Round 6
// 361.394 us; speedup vs baseline: 1.0821x; 1.0821x over previous
//
#include <hip/hip_runtime.h>
#include <hip/hip_bf16.h>

#define DD 96

// ---------------- dtype detect ----------------
__global__ void detect_idx_kernel(const unsigned long long* __restrict__ idx,
                                  int* __restrict__ flag,
                                  unsigned long long nmax) {
    __shared__ int bad;
    if (threadIdx.x == 0) bad = 0;
    __syncthreads();
    unsigned long long v = idx[threadIdx.x];
    if (v >= nmax) bad = 1;
    __syncthreads();
    if (threadIdx.x == 0) *flag = bad ? 0 : 1;  // 1 => int64 layout
}

__device__ __forceinline__ int load_idx(const void* eidx, int isI64, int pos) {
    return isI64 ? (int)((const long long*)eidx)[pos] : ((const int*)eidx)[pos];
}

// ---------------- CSR build ----------------
__global__ __launch_bounds__(256) void hist_kernel(
    const void* __restrict__ eidx, const int* __restrict__ flag,
    int* __restrict__ deg, int E, int n) {
    int e0 = (blockIdx.x * 256 + threadIdx.x) * 4;
    if (e0 >= E) return;
    const int isI64 = *flag;
    if (e0 + 4 <= E) {
        int d0 = load_idx(eidx, isI64, E + e0 + 0);
        int d1 = load_idx(eidx, isI64, E + e0 + 1);
        int d2 = load_idx(eidx, isI64, E + e0 + 2);
        int d3 = load_idx(eidx, isI64, E + e0 + 3);
        if ((unsigned)d0 < (unsigned)n) atomicAdd(&deg[d0], 1);
        if ((unsigned)d1 < (unsigned)n) atomicAdd(&deg[d1], 1);
        if ((unsigned)d2 < (unsigned)n) atomicAdd(&deg[d2], 1);
        if ((unsigned)d3 < (unsigned)n) atomicAdd(&deg[d3], 1);
    } else {
        for (int e = e0; e < E; ++e) {
            int d = load_idx(eidx, isI64, E + e);
            if ((unsigned)d < (unsigned)n) atomicAdd(&deg[d], 1);
        }
    }
}

#define SCAN_BLOCK 256
#define SCAN_ELEMS 1024

__global__ __launch_bounds__(SCAN_BLOCK) void scan1_kernel(
    const int* __restrict__ deg, int* __restrict__ partial,
    int* __restrict__ blockSums, int n) {
    __shared__ int sh[SCAN_BLOCK];
    int base = blockIdx.x * SCAN_ELEMS;
    int vals[4];
    int tsum = 0;
    #pragma unroll
    for (int u = 0; u < 4; ++u) {
        int idx = base + threadIdx.x * 4 + u;
        vals[u] = (idx < n) ? deg[idx] : 0;
        tsum += vals[u];
    }
    sh[threadIdx.x] = tsum;
    __syncthreads();
    int v = tsum;
    for (int off = 1; off < SCAN_BLOCK; off <<= 1) {
        int o = (threadIdx.x >= off) ? sh[threadIdx.x - off] : 0;
        __syncthreads();
        v += o;
        sh[threadIdx.x] = v;
        __syncthreads();
    }
    int run = v - tsum;
    #pragma unroll
    for (int u = 0; u < 4; ++u) {
        int idx = base + threadIdx.x * 4 + u;
        if (idx < n) partial[idx] = run;
        run += vals[u];
    }
    if (threadIdx.x == SCAN_BLOCK - 1) blockSums[blockIdx.x] = v;
}

__global__ __launch_bounds__(256) void scan2_kernel(int* __restrict__ blockSums, int nb) {
    __shared__ int sh[256];
    int v = (threadIdx.x < nb) ? blockSums[threadIdx.x] : 0;
    sh[threadIdx.x] = v;
    __syncthreads();
    int inc = v;
    for (int off = 1; off < 256; off <<= 1) {
        int o = (threadIdx.x >= off) ? sh[threadIdx.x - off] : 0;
        __syncthreads();
        inc += o;
        sh[threadIdx.x] = inc;
        __syncthreads();
    }
    if (threadIdx.x < nb) blockSums[threadIdx.x] = inc - v;
}

__global__ __launch_bounds__(256) void scan3_kernel(
    const int* __restrict__ partial, const int* __restrict__ blockSums,
    int* __restrict__ offsets, int* __restrict__ cursor, int n, int E) {
    int i = blockIdx.x * 256 + threadIdx.x;
    if (i < n) {
        int o = partial[i] + blockSums[i >> 10];
        offsets[i] = o;
        cursor[i] = o;
    }
    if (i == n) offsets[n] = E;
}

__global__ __launch_bounds__(256) void bucket_kernel(
    const void* __restrict__ eidx, const int* __restrict__ flag,
    int* __restrict__ cursor, int* __restrict__ ssrc, int E, int n) {
    int e0 = (blockIdx.x * 256 + threadIdx.x) * 4;
    if (e0 >= E) return;
    const int isI64 = *flag;
    if (e0 + 4 <= E) {
        int s0 = load_idx(eidx, isI64, e0 + 0);
        int s1 = load_idx(eidx, isI64, e0 + 1);
        int s2 = load_idx(eidx, isI64, e0 + 2);
        int s3 = load_idx(eidx, isI64, e0 + 3);
        int d0 = load_idx(eidx, isI64, E + e0 + 0);
        int d1 = load_idx(eidx, isI64, E + e0 + 1);
        int d2 = load_idx(eidx, isI64, E + e0 + 2);
        int d3 = load_idx(eidx, isI64, E + e0 + 3);
        bool v0 = (unsigned)s0 < (unsigned)n && (unsigned)d0 < (unsigned)n;
        bool v1 = (unsigned)s1 < (unsigned)n && (unsigned)d1 < (unsigned)n;
        bool v2 = (unsigned)s2 < (unsigned)n && (unsigned)d2 < (unsigned)n;
        bool v3 = (unsigned)s3 < (unsigned)n && (unsigned)d3 < (unsigned)n;
        int p0 = v0 ? atomicAdd(&cursor[d0], 1) : 0;
        int p1 = v1 ? atomicAdd(&cursor[d1], 1) : 0;
        int p2 = v2 ? atomicAdd(&cursor[d2], 1) : 0;
        int p3 = v3 ? atomicAdd(&cursor[d3], 1) : 0;
        if (v0) ssrc[p0] = s0;
        if (v1) ssrc[p1] = s1;
        if (v2) ssrc[p2] = s2;
        if (v3) ssrc[p3] = s3;
    } else {
        for (int e = e0; e < E; ++e) {
            int s = load_idx(eidx, isI64, e);
            int d = load_idx(eidx, isI64, E + e);
            if ((unsigned)s >= (unsigned)n || (unsigned)d >= (unsigned)n) continue;
            int pos = atomicAdd(&cursor[d], 1);
            ssrc[pos] = s;
        }
    }
}

// ---------------- gather aggregation (no atomics) ----------------
__global__ __launch_bounds__(256) void gather_agg_kernel(
    const float* __restrict__ feat, const int* __restrict__ offsets,
    const int* __restrict__ ssrc, float* __restrict__ agg, int n) {
    long long t = (long long)blockIdx.x * 256 + threadIdx.x;
    if (t >= (long long)n * 24) return;
    int i = (int)(t / 24);
    int c = (int)(t % 24);
    int beg = offsets[i], end = offsets[i + 1];
    float4 accA = make_float4(0.f, 0.f, 0.f, 0.f);
    float4 accB = make_float4(0.f, 0.f, 0.f, 0.f);
    int j = beg;
    for (; j + 4 <= end; j += 4) {
        int s0 = ssrc[j + 0];
        int s1 = ssrc[j + 1];
        int s2 = ssrc[j + 2];
        int s3 = ssrc[j + 3];
        float4 v0 = ((const float4*)(feat + (size_t)s0 * DD))[c];
        float4 v1 = ((const float4*)(feat + (size_t)s1 * DD))[c];
        float4 v2 = ((const float4*)(feat + (size_t)s2 * DD))[c];
        float4 v3 = ((const float4*)(feat + (size_t)s3 * DD))[c];
        accA.x += v0.x; accA.y += v0.y; accA.z += v0.z; accA.w += v0.w;
        accB.x += v1.x; accB.y += v1.y; accB.z += v1.z; accB.w += v1.w;
        accA.x += v2.x; accA.y += v2.y; accA.z += v2.z; accA.w += v2.w;
        accB.x += v3.x; accB.y += v3.y; accB.z += v3.z; accB.w += v3.w;
    }
    for (; j < end; ++j) {
        int s = ssrc[j];
        float4 v = ((const float4*)(feat + (size_t)s * DD))[c];
        accA.x += v.x; accA.y += v.y; accA.z += v.z; accA.w += v.w;
    }
    accA.x += accB.x; accA.y += accB.y; accA.z += accB.z; accA.w += accB.w;
    ((float4*)(agg + (size_t)i * DD))[c] = accA;
}

// ---------------- fallback: atomic scatter ----------------
__global__ __launch_bounds__(256) void scatter_add_kernel(
    const float* __restrict__ feat, const void* __restrict__ eidx,
    const int* __restrict__ flag, float* __restrict__ agg,
    int E, int n) {
    long long t = (long long)blockIdx.x * 256 + threadIdx.x;
    if (t >= (long long)E * 24) return;
    int e = (int)(t / 24);
    int c = (int)(t % 24);
    int isI64 = *flag;
    int s = load_idx(eidx, isI64, e);
    int d = load_idx(eidx, isI64, E + e);
    if ((unsigned)s >= (unsigned)n || (unsigned)d >= (unsigned)n) return;
    const float4 v = ((const float4*)(feat + (size_t)s * DD))[c];
    float* o = agg + (size_t)d * DD + (size_t)c * 4;
    atomicAdd(o + 0, v.x);
    atomicAdd(o + 1, v.y);
    atomicAdd(o + 2, v.z);
    atomicAdd(o + 3, v.w);
}

// ---------------- fast dual-linear: 64 nodes/block, row-split only ----------
// Block = 256 threads = 64 lanes(nodes) x 4 quarters(24 cols). 1 node/thread.
// W staged in one 36 KB LDS buffer, 2 phases (Wrel/A then Wroot/X) -> each
// node row fetched once per phase (no cross-block column split => no 4x
// re-fetch, the R5 regression). Grid = ceil(N/64) = 782 -> ~3 blocks/CU.
// REQUIRES out disjoint from A and X.
__global__ __launch_bounds__(256, 4) void linear64_kernel(
    const float* __restrict__ A, const float* __restrict__ X,
    const float* __restrict__ Wrel, const float* __restrict__ bias,
    const float* __restrict__ Wroot, float* __restrict__ out,
    int n, int do_relu) {
    __shared__ float wlds[DD * DD];  // 36864 B

    const int lane = threadIdx.x & 63;
    const int q = threadIdx.x >> 6;       // wave-uniform
    const int j0 = q * 24;
    const int node = blockIdx.x * 64 + lane;
    const bool act = (node < n);
    const int r = act ? node : 0;

    float acc[24];
    {
        const float4* bq = (const float4*)(bias + j0);
        #pragma unroll
        for (int jj = 0; jj < 6; ++jj) {
            float4 b = bq[jj];
            acc[jj*4+0] = b.x; acc[jj*4+1] = b.y;
            acc[jj*4+2] = b.z; acc[jj*4+3] = b.w;
        }
    }

    const float* srcs[2] = {A, X};
    const float* mats[2] = {Wrel, Wroot};

    for (int phase = 0; phase < 2; ++phase) {
        {
            const float4* wg = (const float4*)mats[phase];
            float4* wl = (float4*)wlds;
            #pragma unroll
            for (int i = 0; i < 9; ++i)
                wl[threadIdx.x + i * 256] = wg[threadIdx.x + i * 256];
        }
        __syncthreads();

        const float* row = srcs[phase] + (size_t)r * DD;

        for (int kk = 0; kk < DD; kk += 4) {
            float4 a4 = *(const float4*)(row + kk);
            const float av[4] = {a4.x, a4.y, a4.z, a4.w};
            #pragma unroll
            for (int u = 0; u < 4; ++u) {
                const float4* wrow = (const float4*)(&wlds[(kk + u) * DD + j0]);
                const float ka = av[u];
                #pragma unroll
                for (int jj = 0; jj < 6; ++jj) {
                    float4 w = wrow[jj];
                    acc[jj*4+0] = fmaf(ka, w.x, acc[jj*4+0]);
                    acc[jj*4+1] = fmaf(ka, w.y, acc[jj*4+1]);
                    acc[jj*4+2] = fmaf(ka, w.z, acc[jj*4+2]);
                    acc[jj*4+3] = fmaf(ka, w.w, acc[jj*4+3]);
                }
            }
        }
        if (phase == 0) __syncthreads();  // wlds reuse
    }

    if (act) {
        float4* o = (float4*)(out + (size_t)node * DD + j0);
        #pragma unroll
        for (int jj = 0; jj < 6; ++jj) {
            float4 v = make_float4(acc[jj*4+0], acc[jj*4+1],
                                   acc[jj*4+2], acc[jj*4+3]);
            if (do_relu) {
                v.x = fmaxf(v.x, 0.f); v.y = fmaxf(v.y, 0.f);
                v.z = fmaxf(v.z, 0.f); v.w = fmaxf(v.w, 0.f);
            }
            o[jj] = v;
        }
    }
}

// ---------------- alias-safe dual-linear (fallbacks only) ----------------
__global__ __launch_bounds__(256) void linear_kernel(
    const float* __restrict__ A, const float* __restrict__ X,
    const float* __restrict__ Wrel, const float* __restrict__ bias,
    const float* __restrict__ Wroot, float* __restrict__ out,
    int n, int do_relu) {
    __shared__ float wlds[DD * DD];

    const int lane = threadIdx.x & 63;
    const int q = threadIdx.x >> 6;
    const int j0 = q * 24;
    const int m0 = blockIdx.x * 128 + lane;
    const int m1 = m0 + 64;
    const bool act0 = (m0 < n), act1 = (m1 < n);
    const int r0 = act0 ? m0 : 0;
    const int r1 = act1 ? m1 : 0;

    float acc0[24], acc1[24];
    {
        const float4* bq = (const float4*)(bias + j0);
        #pragma unroll
        for (int jj = 0; jj < 6; ++jj) {
            float4 b = bq[jj];
            acc0[jj*4+0] = b.x; acc0[jj*4+1] = b.y;
            acc0[jj*4+2] = b.z; acc0[jj*4+3] = b.w;
            acc1[jj*4+0] = b.x; acc1[jj*4+1] = b.y;
            acc1[jj*4+2] = b.z; acc1[jj*4+3] = b.w;
        }
    }

    const float* srcs[2] = {A, X};
    const float* mats[2] = {Wrel, Wroot};

    for (int phase = 0; phase < 2; ++phase) {
        {
            const float4* wg = (const float4*)mats[phase];
            float4* wl = (float4*)wlds;
            #pragma unroll
            for (int i = 0; i < 9; ++i)
                wl[threadIdx.x + i * 256] = wg[threadIdx.x + i * 256];
        }
        __syncthreads();

        const float* row0 = srcs[phase] + (size_t)r0 * DD;
        const float* row1 = srcs[phase] + (size_t)r1 * DD;

        for (int kk = 0; kk < DD; kk += 4) {
            float4 a0 = *(const float4*)(row0 + kk);
            float4 a1 = *(const float4*)(row1 + kk);
            const float av0[4] = {a0.x, a0.y, a0.z, a0.w};
            const float av1[4] = {a1.x, a1.y, a1.z, a1.w};
            #pragma unroll
            for (int u = 0; u < 4; ++u) {
                const float4* wrow = (const float4*)(&wlds[(kk + u) * DD + j0]);
                const float k0 = av0[u], k1 = av1[u];
                #pragma unroll
                for (int jj = 0; jj < 6; ++jj) {
                    float4 w = wrow[jj];
                    acc0[jj*4+0] = fmaf(k0, w.x, acc0[jj*4+0]);
                    acc0[jj*4+1] = fmaf(k0, w.y, acc0[jj*4+1]);
                    acc0[jj*4+2] = fmaf(k0, w.z, acc0[jj*4+2]);
                    acc0[jj*4+3] = fmaf(k0, w.w, acc0[jj*4+3]);
                    acc1[jj*4+0] = fmaf(k1, w.x, acc1[jj*4+0]);
                    acc1[jj*4+1] = fmaf(k1, w.y, acc1[jj*4+1]);
                    acc1[jj*4+2] = fmaf(k1, w.z, acc1[jj*4+2]);
                    acc1[jj*4+3] = fmaf(k1, w.w, acc1[jj*4+3]);
                }
            }
        }
        __syncthreads();
    }

    if (act0) {
        float4* o = (float4*)(out + (size_t)m0 * DD + j0);
        #pragma unroll
        for (int jj = 0; jj < 6; ++jj) {
            float4 v = make_float4(acc0[jj*4+0], acc0[jj*4+1],
                                   acc0[jj*4+2], acc0[jj*4+3]);
            if (do_relu) {
                v.x = fmaxf(v.x, 0.f); v.y = fmaxf(v.y, 0.f);
                v.z = fmaxf(v.z, 0.f); v.w = fmaxf(v.w, 0.f);
            }
            o[jj] = v;
        }
    }
    if (act1) {
        float4* o = (float4*)(out + (size_t)m1 * DD + j0);
        #pragma unroll
        for (int jj = 0; jj < 6; ++jj) {
            float4 v = make_float4(acc1[jj*4+0], acc1[jj*4+1],
                                   acc1[jj*4+2], acc1[jj*4+3]);
            if (do_relu) {
                v.x = fmaxf(v.x, 0.f); v.y = fmaxf(v.y, 0.f);
                v.z = fmaxf(v.z, 0.f); v.w = fmaxf(v.w, 0.f);
            }
            o[jj] = v;
        }
    }
}

extern "C" void kernel_launch(void* const* d_in, const int* in_sizes, int n_in,
                              void* d_out, int out_size, void* d_ws, size_t ws_size,
                              hipStream_t stream) {
    const float* x      = (const float*)d_in[0];
    const void*  eidx   = d_in[1];
    const float* W1_rel = (const float*)d_in[2];
    const float* b1     = (const float*)d_in[3];
    const float* W1_root= (const float*)d_in[4];
    const float* W2_rel = (const float*)d_in[5];
    const float* b2     = (const float*)d_in[6];
    const float* W2_root= (const float*)d_in[7];
    float* out = (float*)d_out;

    const int N = in_sizes[0] / DD;   // 50000
    const int E = in_sizes[1] / 2;    // 800000

    const size_t aggB = (size_t)N * DD * sizeof(float);
    char* base = (char*)d_ws;
    float* agg  = (float*)base;
    int*   flag = (int*)(base + aggB);
    size_t off = (aggB + 15) & ~(size_t)15;
    off += 16;
    int* offsets   = (int*)(base + off); off += (size_t)(N + 1) * 4;
    int* cursor    = (int*)(base + off); off += (size_t)N * 4;
    int* deg       = (int*)(base + off); off += (size_t)N * 4;
    int* partial   = (int*)(base + off); off += (size_t)N * 4;
    int* blockSums = (int*)(base + off); off += 256 * 4;
    int* ssrc      = (int*)(base + off); off += (size_t)E * 4;
    const bool csr_ok = (off <= ws_size) && (N <= SCAN_ELEMS * 256);
    off = (off + 15) & ~(size_t)15;
    float* hbuf = (float*)(base + off); off += aggB;
    const bool h_ok = (off <= ws_size);

    const int linear_blocks = (N + 127) / 128;
    const int lin64_blocks = (N + 63) / 64;
    const int edge_blocks4 = (E + 1023) / 1024;

    detect_idx_kernel<<<1, 256, 0, stream>>>(
        (const unsigned long long*)eidx, flag, (unsigned long long)N);

    if (csr_ok) {
        const int NB = (N + SCAN_ELEMS - 1) / SCAN_ELEMS;
        const int gather_blocks = (int)(((long long)N * 24 + 255) / 256);

        hipMemsetAsync(deg, 0, (size_t)N * 4, stream);
        hist_kernel<<<edge_blocks4, 256, 0, stream>>>(eidx, flag, deg, E, N);
        scan1_kernel<<<NB, SCAN_BLOCK, 0, stream>>>(deg, partial, blockSums, N);
        scan2_kernel<<<1, 256, 0, stream>>>(blockSums, NB);
        scan3_kernel<<<(N + 256) / 256, 256, 0, stream>>>(partial, blockSums,
                                                          offsets, cursor, N, E);
        bucket_kernel<<<edge_blocks4, 256, 0, stream>>>(eidx, flag, cursor, ssrc, E, N);

        float* h = h_ok ? hbuf : out;

        gather_agg_kernel<<<gather_blocks, 256, 0, stream>>>(x, offsets, ssrc, agg, N);
        linear64_kernel<<<lin64_blocks, 256, 0, stream>>>(agg, x, W1_rel, b1, W1_root,
                                                          h, N, 1);
        gather_agg_kernel<<<gather_blocks, 256, 0, stream>>>(h, offsets, ssrc, agg, N);
        if (h_ok) {
            linear64_kernel<<<lin64_blocks, 256, 0, stream>>>(agg, h, W2_rel, b2,
                                                              W2_root, out, N, 0);
        } else {
            linear_kernel<<<linear_blocks, 256, 0, stream>>>(agg, h, W2_rel, b2,
                                                             W2_root, out, N, 0);
        }
    } else {
        const int scatter_blocks = (int)(((long long)E * 24 + 255) / 256);
        hipMemsetAsync(agg, 0, aggB, stream);
        scatter_add_kernel<<<scatter_blocks, 256, 0, stream>>>(x, eidx, flag, agg, E, N);
        linear64_kernel<<<lin64_blocks, 256, 0, stream>>>(agg, x, W1_rel, b1, W1_root,
                                                          out, N, 1);
        hipMemsetAsync(agg, 0, aggB, stream);
        scatter_add_kernel<<<scatter_blocks, 256, 0, stream>>>(out, eidx, flag, agg, E, N);
        linear_kernel<<<linear_blocks, 256, 0, stream>>>(agg, out, W2_rel, b2, W2_root,
                                                         out, N, 0);
    }
}

// Round 7
// 309.435 us; speedup vs baseline: 1.2638x; 1.1679x over previous
//
#include <hip/hip_runtime.h>
#include <hip/hip_bf16.h>

#define DD 96
#define CB_BITS 7
#define CB_SIZE 128            // nodes per coarse bin
#define CB_MAXBINS 512         // supports N <= 65536
#define CBE 2048               // edges per coarse_bin block

// ---------------- dtype detect ----------------
__global__ void detect_idx_kernel(const unsigned long long* __restrict__ idx,
                                  int* __restrict__ flag,
                                  unsigned long long nmax) {
    __shared__ int bad;
    if (threadIdx.x == 0) bad = 0;
    __syncthreads();
    unsigned long long v = idx[threadIdx.x];
    if (v >= nmax) bad = 1;
    __syncthreads();
    if (threadIdx.x == 0) *flag = bad ? 0 : 1;  // 1 => int64 layout
}

__device__ __forceinline__ int load_idx(const void* eidx, int isI64, int pos) {
    return isI64 ? (int)((const long long*)eidx)[pos] : ((const int*)eidx)[pos];
}

__device__ __forceinline__ unsigned int b16(float f) {   // fp32 -> bf16 bits (RNE)
    unsigned int u = __float_as_uint(f);
    return (u + 0x7fffu + ((u >> 16) & 1u)) >> 16;
}
__device__ __forceinline__ unsigned int pack2(float lo, float hi) {
    return b16(lo) | (b16(hi) << 16);
}

// ================= NEW CSR BUILD (coarse-binned counting sort) =============
__global__ __launch_bounds__(256) void hist_coarse_kernel(
    const void* __restrict__ eidx, const int* __restrict__ flag,
    int* __restrict__ coarseHist, int E, int n) {
    __shared__ int ch[CB_MAXBINS];
    for (int i = threadIdx.x; i < CB_MAXBINS; i += 256) ch[i] = 0;
    __syncthreads();
    const int e0 = (blockIdx.x * 256 + threadIdx.x) * 4;
    const int isI64 = *flag;
    #pragma unroll
    for (int u = 0; u < 4; ++u) {
        int e = e0 + u;
        if (e < E) {
            int s = load_idx(eidx, isI64, e);
            int d = load_idx(eidx, isI64, E + e);
            if ((unsigned)s < (unsigned)n && (unsigned)d < (unsigned)n)
                atomicAdd(&ch[d >> CB_BITS], 1);
        }
    }
    __syncthreads();
    for (int i = threadIdx.x; i < CB_MAXBINS; i += 256)
        if (ch[i]) atomicAdd(&coarseHist[i], ch[i]);
}

// one block: exclusive scan of coarseHist[0..CB_MAXBINS) -> coarseOff/cursor
__global__ __launch_bounds__(256) void coarse_scan_kernel(
    const int* __restrict__ coarseHist, int* __restrict__ coarseOff,
    int* __restrict__ coarseCursor, int nbins) {
    __shared__ int sh[256];
    const int tid = threadIdx.x;
    int a0 = coarseHist[2 * tid];
    int a1 = coarseHist[2 * tid + 1];
    int ps = a0 + a1;
    sh[tid] = ps;
    __syncthreads();
    int v = ps;
    for (int off = 1; off < 256; off <<= 1) {
        int o = (tid >= off) ? sh[tid - off] : 0;
        __syncthreads();
        v += o;
        sh[tid] = v;
        __syncthreads();
    }
    int ex = v - ps;
    int i0 = 2 * tid, i1 = i0 + 1;
    if (i0 <= nbins) { coarseOff[i0] = ex;      coarseCursor[i0] = ex; }
    if (i1 <= nbins) { coarseOff[i1] = ex + a0; coarseCursor[i1] = ex + a0; }
}

// block: locally bin CBE edges by dst>>CB_BITS, write contiguous runs
__global__ __launch_bounds__(256) void coarse_bin_kernel(
    const void* __restrict__ eidx, const int* __restrict__ flag,
    int* __restrict__ coarseCursor, uint2* __restrict__ estage,
    int E, int n, int nbins) {
    __shared__ int cnt[CB_MAXBINS];
    __shared__ int pref[CB_MAXBINS];
    __shared__ int cur[CB_MAXBINS];
    __shared__ int gbase[CB_MAXBINS];
    __shared__ uint2 ebuf[CBE];
    __shared__ int tot_sh;
    const int tid = threadIdx.x;
    for (int i = tid; i < CB_MAXBINS; i += 256) cnt[i] = 0;
    __syncthreads();
    const int base = blockIdx.x * CBE;
    const int isI64 = *flag;
    // phase 1: count
    for (int k = tid; k < CBE; k += 256) {
        int e = base + k;
        if (e < E) {
            int s = load_idx(eidx, isI64, e);
            int d = load_idx(eidx, isI64, E + e);
            if ((unsigned)s < (unsigned)n && (unsigned)d < (unsigned)n)
                atomicAdd(&cnt[d >> CB_BITS], 1);
        }
    }
    __syncthreads();
    // phase 2: scan cnt -> pref (exclusive); gbase as scratch
    {
        int a0 = cnt[2 * tid], a1 = cnt[2 * tid + 1];
        int ps = a0 + a1;
        gbase[tid] = ps;
        __syncthreads();
        int v = ps;
        for (int off = 1; off < 256; off <<= 1) {
            int o = (tid >= off) ? gbase[tid - off] : 0;
            __syncthreads();
            v += o;
            gbase[tid] = v;
            __syncthreads();
        }
        int ex = v - ps;
        pref[2 * tid] = ex;      pref[2 * tid + 1] = ex + a0;
        cur[2 * tid]  = ex;      cur[2 * tid + 1]  = ex + a0;
        if (tid == 255) tot_sh = v;
    }
    __syncthreads();
    const int tot = tot_sh;
    // phase 3: place into ebuf grouped by bin
    for (int k = tid; k < CBE; k += 256) {
        int e = base + k;
        if (e < E) {
            int s = load_idx(eidx, isI64, e);
            int d = load_idx(eidx, isI64, E + e);
            if ((unsigned)s < (unsigned)n && (unsigned)d < (unsigned)n) {
                int r = atomicAdd(&cur[d >> CB_BITS], 1);
                ebuf[r] = make_uint2((unsigned)s, (unsigned)d);
            }
        }
    }
    __syncthreads();
    // phase 4: reserve global space per bin
    for (int i = tid; i < nbins; i += 256) {
        int c = cnt[i];
        gbase[i] = c ? atomicAdd(&coarseCursor[i], c) : 0;
    }
    __syncthreads();
    // phase 5: write runs (contiguous per bin)
    for (int k = tid; k < tot; k += 256) {
        int lo = 0, hi = nbins;
        while (hi - lo > 1) {
            int mid = (lo + hi) >> 1;
            if (pref[mid] <= k) lo = mid; else hi = mid;
        }
        int g = gbase[lo] + (k - pref[lo]);
        if (g < E) estage[g] = ebuf[k];
    }
}

// one block per coarse bin: LDS count+scan of its 128 nodes, write offsets
// coalesced, scatter ssrc within an L2-resident window.
__global__ __launch_bounds__(256) void fine_bucket_kernel(
    const uint2* __restrict__ estage, const int* __restrict__ coarseOff,
    int* __restrict__ offsets, int* __restrict__ ssrc,
    int E, int n, int nbins) {
    __shared__ int cnt[CB_SIZE];
    __shared__ int pref[CB_SIZE];
    __shared__ int cur[CB_SIZE];
    const int b = blockIdx.x;
    const int tid = threadIdx.x;
    const int beg = coarseOff[b], end = coarseOff[b + 1];
    if (tid < CB_SIZE) cnt[tid] = 0;
    __syncthreads();
    for (int k = beg + tid; k < end; k += 256)
        atomicAdd(&cnt[estage[k].y & (CB_SIZE - 1)], 1);
    __syncthreads();
    {
        int v = (tid < CB_SIZE) ? cnt[tid] : 0;
        if (tid < CB_SIZE) pref[tid] = v;
        __syncthreads();
        for (int off = 1; off < CB_SIZE; off <<= 1) {
            int o = (tid < CB_SIZE && tid >= off) ? pref[tid - off] : 0;
            __syncthreads();
            if (tid < CB_SIZE) { v += o; pref[tid] = v; }
            __syncthreads();
        }
        if (tid < CB_SIZE) {
            int ex = v - cnt[tid];
            cur[tid] = beg + ex;
            int node = (b << CB_BITS) + tid;
            if (node < n) offsets[node] = beg + ex;
        }
    }
    __syncthreads();
    for (int k = beg + tid; k < end; k += 256) {
        uint2 e = estage[k];
        int pos = atomicAdd(&cur[e.y & (CB_SIZE - 1)], 1);
        if (pos < E) ssrc[pos] = (int)e.x;
    }
    if (b == 0 && tid == 0) offsets[n] = coarseOff[nbins];
}

// ================= bf16 conversion + gather =================
__global__ __launch_bounds__(256) void convert_bf16_kernel(
    const float* __restrict__ in, unsigned short* __restrict__ outb,
    long long nelem) {
    long long i = ((long long)blockIdx.x * 256 + threadIdx.x) * 8;
    if (i + 8 > nelem) return;
    float4 f0 = ((const float4*)(in + i))[0];
    float4 f1 = ((const float4*)(in + i))[1];
    uint4 o;
    o.x = pack2(f0.x, f0.y); o.y = pack2(f0.z, f0.w);
    o.z = pack2(f1.x, f1.y); o.w = pack2(f1.z, f1.w);
    *((uint4*)(outb + i)) = o;
}

__device__ __forceinline__ void acc8(float* a, uint4 w) {
    a[0] += __uint_as_float(w.x << 16); a[1] += __uint_as_float(w.x & 0xffff0000u);
    a[2] += __uint_as_float(w.y << 16); a[3] += __uint_as_float(w.y & 0xffff0000u);
    a[4] += __uint_as_float(w.z << 16); a[5] += __uint_as_float(w.z & 0xffff0000u);
    a[6] += __uint_as_float(w.w << 16); a[7] += __uint_as_float(w.w & 0xffff0000u);
}

// thread = (node i, 8-value chunk c in [0,12)); fp32 accumulate.
__global__ __launch_bounds__(256) void gather_agg_bf16_kernel(
    const unsigned short* __restrict__ xb, const int* __restrict__ offsets,
    const int* __restrict__ ssrc, float* __restrict__ agg, int n) {
    long long t = (long long)blockIdx.x * 256 + threadIdx.x;
    if (t >= (long long)n * 12) return;
    int i = (int)(t / 12);
    int c = (int)(t % 12);
    int beg = offsets[i], end = offsets[i + 1];
    float accA[8] = {0, 0, 0, 0, 0, 0, 0, 0};
    float accB[8] = {0, 0, 0, 0, 0, 0, 0, 0};
    int j = beg;
    for (; j + 4 <= end; j += 4) {
        int s0 = ssrc[j + 0], s1 = ssrc[j + 1];
        int s2 = ssrc[j + 2], s3 = ssrc[j + 3];
        uint4 w0 = ((const uint4*)(xb + (size_t)s0 * DD))[c];
        uint4 w1 = ((const uint4*)(xb + (size_t)s1 * DD))[c];
        uint4 w2 = ((const uint4*)(xb + (size_t)s2 * DD))[c];
        uint4 w3 = ((const uint4*)(xb + (size_t)s3 * DD))[c];
        acc8(accA, w0); acc8(accB, w1); acc8(accA, w2); acc8(accB, w3);
    }
    for (; j < end; ++j) {
        int s = ssrc[j];
        uint4 w = ((const uint4*)(xb + (size_t)s * DD))[c];
        acc8(accA, w);
    }
    float4 o0 = make_float4(accA[0] + accB[0], accA[1] + accB[1],
                            accA[2] + accB[2], accA[3] + accB[3]);
    float4 o1 = make_float4(accA[4] + accB[4], accA[5] + accB[5],
                            accA[6] + accB[6], accA[7] + accB[7]);
    float* orow = agg + (size_t)i * DD + (size_t)c * 8;
    ((float4*)orow)[0] = o0;
    ((float4*)orow)[1] = o1;
}

// ================= OLD CSR BUILD (fallback) =================
__global__ __launch_bounds__(256) void hist_kernel(
    const void* __restrict__ eidx, const int* __restrict__ flag,
    int* __restrict__ deg, int E, int n) {
    int e0 = (blockIdx.x * 256 + threadIdx.x) * 4;
    if (e0 >= E) return;
    const int isI64 = *flag;
    for (int e = e0; e < e0 + 4 && e < E; ++e) {
        int d = load_idx(eidx, isI64, E + e);
        if ((unsigned)d < (unsigned)n) atomicAdd(&deg[d], 1);
    }
}

#define SCAN_BLOCK 256
#define SCAN_ELEMS 1024

__global__ __launch_bounds__(SCAN_BLOCK) void scan1_kernel(
    const int* __restrict__ deg, int* __restrict__ partial,
    int* __restrict__ blockSums, int n) {
    __shared__ int sh[SCAN_BLOCK];
    int base = blockIdx.x * SCAN_ELEMS;
    int vals[4];
    int tsum = 0;
    #pragma unroll
    for (int u = 0; u < 4; ++u) {
        int idx = base + threadIdx.x * 4 + u;
        vals[u] = (idx < n) ? deg[idx] : 0;
        tsum += vals[u];
    }
    sh[threadIdx.x] = tsum;
    __syncthreads();
    int v = tsum;
    for (int off = 1; off < SCAN_BLOCK; off <<= 1) {
        int o = (threadIdx.x >= off) ? sh[threadIdx.x - off] : 0;
        __syncthreads();
        v += o;
        sh[threadIdx.x] = v;
        __syncthreads();
    }
    int run = v - tsum;
    #pragma unroll
    for (int u = 0; u < 4; ++u) {
        int idx = base + threadIdx.x * 4 + u;
        if (idx < n) partial[idx] = run;
        run += vals[u];
    }
    if (threadIdx.x == SCAN_BLOCK - 1) blockSums[blockIdx.x] = v;
}

__global__ __launch_bounds__(256) void scan2_kernel(int* __restrict__ blockSums, int nb) {
    __shared__ int sh[256];
    int v = (threadIdx.x < nb) ? blockSums[threadIdx.x] : 0;
    sh[threadIdx.x] = v;
    __syncthreads();
    int inc = v;
    for (int off = 1; off < 256; off <<= 1) {
        int o = (threadIdx.x >= off) ? sh[threadIdx.x - off] : 0;
        __syncthreads();
        inc += o;
        sh[threadIdx.x] = inc;
        __syncthreads();
    }
    if (threadIdx.x < nb) blockSums[threadIdx.x] = inc - v;
}

__global__ __launch_bounds__(256) void scan3_kernel(
    const int* __restrict__ partial, const int* __restrict__ blockSums,
    int* __restrict__ offsets, int* __restrict__ cursor, int n, int E) {
    int i = blockIdx.x * 256 + threadIdx.x;
    if (i < n) {
        int o = partial[i] + blockSums[i >> 10];
        offsets[i] = o;
        cursor[i] = o;
    }
    if (i == n) offsets[n] = E;
}

__global__ __launch_bounds__(256) void bucket_kernel(
    const void* __restrict__ eidx, const int* __restrict__ flag,
    int* __restrict__ cursor, int* __restrict__ ssrc, int E, int n) {
    int e0 = (blockIdx.x * 256 + threadIdx.x) * 4;
    if (e0 >= E) return;
    const int isI64 = *flag;
    for (int e = e0; e < e0 + 4 && e < E; ++e) {
        int s = load_idx(eidx, isI64, e);
        int d = load_idx(eidx, isI64, E + e);
        if ((unsigned)s >= (unsigned)n || (unsigned)d >= (unsigned)n) continue;
        int pos = atomicAdd(&cursor[d], 1);
        if (pos < E) ssrc[pos] = s;
    }
}

// ---------------- fp32 gather (fallback) ----------------
__global__ __launch_bounds__(256) void gather_agg_kernel(
    const float* __restrict__ feat, const int* __restrict__ offsets,
    const int* __restrict__ ssrc, float* __restrict__ agg, int n) {
    long long t = (long long)blockIdx.x * 256 + threadIdx.x;
    if (t >= (long long)n * 24) return;
    int i = (int)(t / 24);
    int c = (int)(t % 24);
    int beg = offsets[i], end = offsets[i + 1];
    float4 accA = make_float4(0.f, 0.f, 0.f, 0.f);
    float4 accB = make_float4(0.f, 0.f, 0.f, 0.f);
    int j = beg;
    for (; j + 4 <= end; j += 4) {
        int s0 = ssrc[j + 0], s1 = ssrc[j + 1];
        int s2 = ssrc[j + 2], s3 = ssrc[j + 3];
        float4 v0 = ((const float4*)(feat + (size_t)s0 * DD))[c];
        float4 v1 = ((const float4*)(feat + (size_t)s1 * DD))[c];
        float4 v2 = ((const float4*)(feat + (size_t)s2 * DD))[c];
        float4 v3 = ((const float4*)(feat + (size_t)s3 * DD))[c];
        accA.x += v0.x; accA.y += v0.y; accA.z += v0.z; accA.w += v0.w;
        accB.x += v1.x; accB.y += v1.y; accB.z += v1.z; accB.w += v1.w;
        accA.x += v2.x; accA.y += v2.y; accA.z += v2.z; accA.w += v2.w;
        accB.x += v3.x; accB.y += v3.y; accB.z += v3.z; accB.w += v3.w;
    }
    for (; j < end; ++j) {
        int s = ssrc[j];
        float4 v = ((const float4*)(feat + (size_t)s * DD))[c];
        accA.x += v.x; accA.y += v.y; accA.z += v.z; accA.w += v.w;
    }
    accA.x += accB.x; accA.y += accB.y; accA.z += accB.z; accA.w += accB.w;
    ((float4*)(agg + (size_t)i * DD))[c] = accA;
}

// ---------------- fallback: atomic scatter ----------------
__global__ __launch_bounds__(256) void scatter_add_kernel(
    const float* __restrict__ feat, const void* __restrict__ eidx,
    const int* __restrict__ flag, float* __restrict__ agg,
    int E, int n) {
    long long t = (long long)blockIdx.x * 256 + threadIdx.x;
    if (t >= (long long)E * 24) return;
    int e = (int)(t / 24);
    int c = (int)(t % 24);
    int isI64 = *flag;
    int s = load_idx(eidx, isI64, e);
    int d = load_idx(eidx, isI64, E + e);
    if ((unsigned)s >= (unsigned)n || (unsigned)d >= (unsigned)n) return;
    const float4 v = ((const float4*)(feat + (size_t)s * DD))[c];
    float* o = agg + (size_t)d * DD + (size_t)c * 4;
    atomicAdd(o + 0, v.x);
    atomicAdd(o + 1, v.y);
    atomicAdd(o + 2, v.z);
    atomicAdd(o + 3, v.w);
}

// ---------------- fast dual-linear: 64 nodes/block ----------
// Optionally writes bf16 copy of output to hb (for the next gather).
__global__ __launch_bounds__(256, 4) void linear64_kernel(
    const float* __restrict__ A, const float* __restrict__ X,
    const float* __restrict__ Wrel, const float* __restrict__ bias,
    const float* __restrict__ Wroot, float* __restrict__ out,
    unsigned short* __restrict__ hb, int n, int do_relu) {
    __shared__ float wlds[DD * DD];  // 36864 B

    const int lane = threadIdx.x & 63;
    const int q = threadIdx.x >> 6;
    const int j0 = q * 24;
    const int node = blockIdx.x * 64 + lane;
    const bool act = (node < n);
    const int r = act ? node : 0;

    float acc[24];
    {
        const float4* bq = (const float4*)(bias + j0);
        #pragma unroll
        for (int jj = 0; jj < 6; ++jj) {
            float4 b = bq[jj];
            acc[jj*4+0] = b.x; acc[jj*4+1] = b.y;
            acc[jj*4+2] = b.z; acc[jj*4+3] = b.w;
        }
    }

    const float* srcs[2] = {A, X};
    const float* mats[2] = {Wrel, Wroot};

    for (int phase = 0; phase < 2; ++phase) {
        {
            const float4* wg = (const float4*)mats[phase];
            float4* wl = (float4*)wlds;
            #pragma unroll
            for (int i = 0; i < 9; ++i)
                wl[threadIdx.x + i * 256] = wg[threadIdx.x + i * 256];
        }
        __syncthreads();

        const float* row = srcs[phase] + (size_t)r * DD;

        for (int kk = 0; kk < DD; kk += 4) {
            float4 a4 = *(const float4*)(row + kk);
            const float av[4] = {a4.x, a4.y, a4.z, a4.w};
            #pragma unroll
            for (int u = 0; u < 4; ++u) {
                const float4* wrow = (const float4*)(&wlds[(kk + u) * DD + j0]);
                const float ka = av[u];
                #pragma unroll
                for (int jj = 0; jj < 6; ++jj) {
                    float4 w = wrow[jj];
                    acc[jj*4+0] = fmaf(ka, w.x, acc[jj*4+0]);
                    acc[jj*4+1] = fmaf(ka, w.y, acc[jj*4+1]);
                    acc[jj*4+2] = fmaf(ka, w.z, acc[jj*4+2]);
                    acc[jj*4+3] = fmaf(ka, w.w, acc[jj*4+3]);
                }
            }
        }
        if (phase == 0) __syncthreads();
    }

    if (act) {
        float v[24];
        #pragma unroll
        for (int j = 0; j < 24; ++j)
            v[j] = do_relu ? fmaxf(acc[j], 0.f) : acc[j];
        float4* o = (float4*)(out + (size_t)node * DD + j0);
        #pragma unroll
        for (int jj = 0; jj < 6; ++jj)
            o[jj] = make_float4(v[jj*4+0], v[jj*4+1], v[jj*4+2], v[jj*4+3]);
        if (hb) {
            unsigned short* hrow = hb + (size_t)node * DD + j0;
            #pragma unroll
            for (int g = 0; g < 3; ++g) {
                uint4 p;
                p.x = pack2(v[g*8+0], v[g*8+1]);
                p.y = pack2(v[g*8+2], v[g*8+3]);
                p.z = pack2(v[g*8+4], v[g*8+5]);
                p.w = pack2(v[g*8+6], v[g*8+7]);
                ((uint4*)hrow)[g] = p;
            }
        }
    }
}

// ---------------- alias-safe dual-linear (deep fallback) ----------------
__global__ __launch_bounds__(256) void linear_kernel(
    const float* __restrict__ A, const float* __restrict__ X,
    const float* __restrict__ Wrel, const float* __restrict__ bias,
    const float* __restrict__ Wroot, float* __restrict__ out,
    int n, int do_relu) {
    __shared__ float wlds[DD * DD];
    const int lane = threadIdx.x & 63;
    const int q = threadIdx.x >> 6;
    const int j0 = q * 24;
    const int m0 = blockIdx.x * 128 + lane;
    const int m1 = m0 + 64;
    const bool act0 = (m0 < n), act1 = (m1 < n);
    const int r0 = act0 ? m0 : 0;
    const int r1 = act1 ? m1 : 0;

    float acc0[24], acc1[24];
    {
        const float4* bq = (const float4*)(bias + j0);
        #pragma unroll
        for (int jj = 0; jj < 6; ++jj) {
            float4 b = bq[jj];
            acc0[jj*4+0] = b.x; acc0[jj*4+1] = b.y;
            acc0[jj*4+2] = b.z; acc0[jj*4+3] = b.w;
            acc1[jj*4+0] = b.x; acc1[jj*4+1] = b.y;
            acc1[jj*4+2] = b.z; acc1[jj*4+3] = b.w;
        }
    }
    const float* srcs[2] = {A, X};
    const float* mats[2] = {Wrel, Wroot};
    for (int phase = 0; phase < 2; ++phase) {
        {
            const float4* wg = (const float4*)mats[phase];
            float4* wl = (float4*)wlds;
            #pragma unroll
            for (int i = 0; i < 9; ++i)
                wl[threadIdx.x + i * 256] = wg[threadIdx.x + i * 256];
        }
        __syncthreads();
        const float* row0 = srcs[phase] + (size_t)r0 * DD;
        const float* row1 = srcs[phase] + (size_t)r1 * DD;
        for (int kk = 0; kk < DD; kk += 4) {
            float4 a0 = *(const float4*)(row0 + kk);
            float4 a1 = *(const float4*)(row1 + kk);
            const float av0[4] = {a0.x, a0.y, a0.z, a0.w};
            const float av1[4] = {a1.x, a1.y, a1.z, a1.w};
            #pragma unroll
            for (int u = 0; u < 4; ++u) {
                const float4* wrow = (const float4*)(&wlds[(kk + u) * DD + j0]);
                const float k0 = av0[u], k1 = av1[u];
                #pragma unroll
                for (int jj = 0; jj < 6; ++jj) {
                    float4 w = wrow[jj];
                    acc0[jj*4+0] = fmaf(k0, w.x, acc0[jj*4+0]);
                    acc0[jj*4+1] = fmaf(k0, w.y, acc0[jj*4+1]);
                    acc0[jj*4+2] = fmaf(k0, w.z, acc0[jj*4+2]);
                    acc0[jj*4+3] = fmaf(k0, w.w, acc0[jj*4+3]);
                    acc1[jj*4+0] = fmaf(k1, w.x, acc1[jj*4+0]);
                    acc1[jj*4+1] = fmaf(k1, w.y, acc1[jj*4+1]);
                    acc1[jj*4+2] = fmaf(k1, w.z, acc1[jj*4+2]);
                    acc1[jj*4+3] = fmaf(k1, w.w, acc1[jj*4+3]);
                }
            }
        }
        __syncthreads();
    }
    if (act0) {
        float4* o = (float4*)(out + (size_t)m0 * DD + j0);
        #pragma unroll
        for (int jj = 0; jj < 6; ++jj) {
            float4 v = make_float4(acc0[jj*4+0], acc0[jj*4+1],
                                   acc0[jj*4+2], acc0[jj*4+3]);
            if (do_relu) {
                v.x = fmaxf(v.x, 0.f); v.y = fmaxf(v.y, 0.f);
                v.z = fmaxf(v.z, 0.f); v.w = fmaxf(v.w, 0.f);
            }
            o[jj] = v;
        }
    }
    if (act1) {
        float4* o = (float4*)(out + (size_t)m1 * DD + j0);
        #pragma unroll
        for (int jj = 0; jj < 6; ++jj) {
            float4 v = make_float4(acc1[jj*4+0], acc1[jj*4+1],
                                   acc1[jj*4+2], acc1[jj*4+3]);
            if (do_relu) {
                v.x = fmaxf(v.x, 0.f); v.y = fmaxf(v.y, 0.f);
                v.z = fmaxf(v.z, 0.f); v.w = fmaxf(v.w, 0.f);
            }
            o[jj] = v;
        }
    }
}

extern "C" void kernel_launch(void* const* d_in, const int* in_sizes, int n_in,
                              void* d_out, int out_size, void* d_ws, size_t ws_size,
                              hipStream_t stream) {
    const float* x      = (const float*)d_in[0];
    const void*  eidx   = d_in[1];
    const float* W1_rel = (const float*)d_in[2];
    const float* b1     = (const float*)d_in[3];
    const float* W1_root= (const float*)d_in[4];
    const float* W2_rel = (const float*)d_in[5];
    const float* b2     = (const float*)d_in[6];
    const float* W2_root= (const float*)d_in[7];
    float* out = (float*)d_out;

    const int N = in_sizes[0] / DD;   // 50000
    const int E = in_sizes[1] / 2;    // 800000
    const int nbins = (N + CB_SIZE - 1) >> CB_BITS;

    const size_t aggB = (size_t)N * DD * sizeof(float);
    const long long nelem = (long long)N * DD;
    char* base = (char*)d_ws;
    size_t off = 0;
    auto alloc = [&](size_t bytes) { size_t o = off; off = (off + bytes + 15) & ~(size_t)15; return base + o; };

    float* agg        = (float*)alloc(aggB);
    int*   flag       = (int*)  alloc(16);
    int*   offsets    = (int*)  alloc((size_t)(N + 1) * 4);
    int*   ssrc       = (int*)  alloc((size_t)E * 4);
    int*   coarseHist = (int*)  alloc(CB_MAXBINS * 4);
    int*   coarseOff  = (int*)  alloc((CB_MAXBINS + 1) * 4);
    int*   coarseCur  = (int*)  alloc((CB_MAXBINS + 1) * 4);
    int*   cursor     = (int*)  alloc((size_t)N * 4);
    int*   deg        = (int*)  alloc((size_t)N * 4);
    int*   partial    = (int*)  alloc((size_t)N * 4);
    int*   blockSums  = (int*)  alloc(256 * 4);
    const bool csr_ok = (off <= ws_size) && (N <= SCAN_ELEMS * 256);
    float* hbuf       = (float*)alloc(aggB);
    const bool h_ok   = (off <= ws_size);
    uint2* estage     = (uint2*)alloc((size_t)E * 8);
    const bool coarse_ok = (off <= ws_size) && (nbins <= CB_MAXBINS);
    unsigned short* xb = (unsigned short*)alloc((size_t)nelem * 2);
    unsigned short* hb = (unsigned short*)alloc((size_t)nelem * 2);
    const bool bf_ok  = (off <= ws_size);

    const int linear_blocks = (N + 127) / 128;
    const int lin64_blocks = (N + 63) / 64;
    const int edge_blocks4 = (E + 1023) / 1024;

    detect_idx_kernel<<<1, 256, 0, stream>>>(
        (const unsigned long long*)eidx, flag, (unsigned long long)N);

    if (csr_ok && h_ok) {
        // ---- CSR build ----
        if (coarse_ok) {
            hipMemsetAsync(coarseHist, 0, CB_MAXBINS * 4, stream);
            hist_coarse_kernel<<<edge_blocks4, 256, 0, stream>>>(
                eidx, flag, coarseHist, E, N);
            coarse_scan_kernel<<<1, 256, 0, stream>>>(
                coarseHist, coarseOff, coarseCur, nbins);
            coarse_bin_kernel<<<(E + CBE - 1) / CBE, 256, 0, stream>>>(
                eidx, flag, coarseCur, estage, E, N, nbins);
            fine_bucket_kernel<<<nbins, 256, 0, stream>>>(
                estage, coarseOff, offsets, ssrc, E, N, nbins);
        } else {
            const int NB = (N + SCAN_ELEMS - 1) / SCAN_ELEMS;
            hipMemsetAsync(deg, 0, (size_t)N * 4, stream);
            hist_kernel<<<edge_blocks4, 256, 0, stream>>>(eidx, flag, deg, E, N);
            scan1_kernel<<<NB, SCAN_BLOCK, 0, stream>>>(deg, partial, blockSums, N);
            scan2_kernel<<<1, 256, 0, stream>>>(blockSums, NB);
            scan3_kernel<<<(N + 256) / 256, 256, 0, stream>>>(
                partial, blockSums, offsets, cursor, N, E);
            bucket_kernel<<<edge_blocks4, 256, 0, stream>>>(
                eidx, flag, cursor, ssrc, E, N);
        }
        // ---- layers ----
        if (bf_ok) {
            const int conv_blocks = (int)((nelem / 8 + 255) / 256);
            const int gb = (int)(((long long)N * 12 + 255) / 256);
            convert_bf16_kernel<<<conv_blocks, 256, 0, stream>>>(x, xb, nelem);
            gather_agg_bf16_kernel<<<gb, 256, 0, stream>>>(xb, offsets, ssrc, agg, N);
            linear64_kernel<<<lin64_blocks, 256, 0, stream>>>(
                agg, x, W1_rel, b1, W1_root, hbuf, hb, N, 1);
            gather_agg_bf16_kernel<<<gb, 256, 0, stream>>>(hb, offsets, ssrc, agg, N);
            linear64_kernel<<<lin64_blocks, 256, 0, stream>>>(
                agg, hbuf, W2_rel, b2, W2_root, out, (unsigned short*)nullptr, N, 0);
        } else {
            const int gb = (int)(((long long)N * 24 + 255) / 256);
            gather_agg_kernel<<<gb, 256, 0, stream>>>(x, offsets, ssrc, agg, N);
            linear64_kernel<<<lin64_blocks, 256, 0, stream>>>(
                agg, x, W1_rel, b1, W1_root, hbuf, (unsigned short*)nullptr, N, 1);
            gather_agg_kernel<<<gb, 256, 0, stream>>>(hbuf, offsets, ssrc, agg, N);
            linear64_kernel<<<lin64_blocks, 256, 0, stream>>>(
                agg, hbuf, W2_rel, b2, W2_root, out, (unsigned short*)nullptr, N, 0);
        }
    } else {
        const int scatter_blocks = (int)(((long long)E * 24 + 255) / 256);
        hipMemsetAsync(agg, 0, aggB, stream);
        scatter_add_kernel<<<scatter_blocks, 256, 0, stream>>>(x, eidx, flag, agg, E, N);
        linear64_kernel<<<lin64_blocks, 256, 0, stream>>>(
            agg, x, W1_rel, b1, W1_root, out, (unsigned short*)nullptr, N, 1);
        hipMemsetAsync(agg, 0, aggB, stream);
        scatter_add_kernel<<<scatter_blocks, 256, 0, stream>>>(out, eidx, flag, agg, E, N);
        linear_kernel<<<linear_blocks, 256, 0, stream>>>(agg, out, W2_rel, b2, W2_root,
                                                         out, N, 0);
    }
}

// Round 8
// 218.965 us; speedup vs baseline: 1.7859x; 1.4132x over previous
//
#include <hip/hip_runtime.h>
#include <hip/hip_bf16.h>

#define DD 96
#define CB_BITS 7
#define CB_SIZE 128            // nodes per coarse bin
#define CB_MAXBINS 512         // supports N <= 65536
#define CBE 2048               // edges per coarse_bin block

typedef __attribute__((ext_vector_type(8))) short short8;
typedef __attribute__((ext_vector_type(4))) float floatx4;

// ---------------- dtype detect ----------------
__global__ void detect_idx_kernel(const unsigned long long* __restrict__ idx,
                                  int* __restrict__ flag,
                                  unsigned long long nmax) {
    __shared__ int bad;
    if (threadIdx.x == 0) bad = 0;
    __syncthreads();
    unsigned long long v = idx[threadIdx.x];
    if (v >= nmax) bad = 1;
    __syncthreads();
    if (threadIdx.x == 0) *flag = bad ? 0 : 1;  // 1 => int64 layout
}

__device__ __forceinline__ int load_idx(const void* eidx, int isI64, int pos) {
    return isI64 ? (int)((const long long*)eidx)[pos] : ((const int*)eidx)[pos];
}

__device__ __forceinline__ unsigned int b16(float f) {   // fp32 -> bf16 bits (RNE)
    unsigned int u = __float_as_uint(f);
    return (u + 0x7fffu + ((u >> 16) & 1u)) >> 16;
}
__device__ __forceinline__ unsigned int pack2(float lo, float hi) {
    return b16(lo) | (b16(hi) << 16);
}

// ================= CSR BUILD (coarse-binned counting sort) =============
__global__ __launch_bounds__(256) void hist_coarse_kernel(
    const void* __restrict__ eidx, const int* __restrict__ flag,
    int* __restrict__ coarseHist, int E, int n) {
    __shared__ int ch[CB_MAXBINS];
    for (int i = threadIdx.x; i < CB_MAXBINS; i += 256) ch[i] = 0;
    __syncthreads();
    const int e0 = (blockIdx.x * 256 + threadIdx.x) * 4;
    const int isI64 = *flag;
    #pragma unroll
    for (int u = 0; u < 4; ++u) {
        int e = e0 + u;
        if (e < E) {
            int s = load_idx(eidx, isI64, e);
            int d = load_idx(eidx, isI64, E + e);
            if ((unsigned)s < (unsigned)n && (unsigned)d < (unsigned)n)
                atomicAdd(&ch[d >> CB_BITS], 1);
        }
    }
    __syncthreads();
    for (int i = threadIdx.x; i < CB_MAXBINS; i += 256)
        if (ch[i]) atomicAdd(&coarseHist[i], ch[i]);
}

__global__ __launch_bounds__(256) void coarse_scan_kernel(
    const int* __restrict__ coarseHist, int* __restrict__ coarseOff,
    int* __restrict__ coarseCursor, int nbins) {
    __shared__ int sh[256];
    const int tid = threadIdx.x;
    int a0 = coarseHist[2 * tid];
    int a1 = coarseHist[2 * tid + 1];
    int ps = a0 + a1;
    sh[tid] = ps;
    __syncthreads();
    int v = ps;
    for (int off = 1; off < 256; off <<= 1) {
        int o = (tid >= off) ? sh[tid - off] : 0;
        __syncthreads();
        v += o;
        sh[tid] = v;
        __syncthreads();
    }
    int ex = v - ps;
    int i0 = 2 * tid, i1 = i0 + 1;
    if (i0 <= nbins) { coarseOff[i0] = ex;      coarseCursor[i0] = ex; }
    if (i1 <= nbins) { coarseOff[i1] = ex + a0; coarseCursor[i1] = ex + a0; }
}

__global__ __launch_bounds__(256) void coarse_bin_kernel(
    const void* __restrict__ eidx, const int* __restrict__ flag,
    int* __restrict__ coarseCursor, uint2* __restrict__ estage,
    int E, int n, int nbins) {
    __shared__ int cnt[CB_MAXBINS];
    __shared__ int pref[CB_MAXBINS];
    __shared__ int cur[CB_MAXBINS];
    __shared__ int gbase[CB_MAXBINS];
    __shared__ uint2 ebuf[CBE];
    __shared__ int tot_sh;
    const int tid = threadIdx.x;
    for (int i = tid; i < CB_MAXBINS; i += 256) cnt[i] = 0;
    __syncthreads();
    const int base = blockIdx.x * CBE;
    const int isI64 = *flag;
    for (int k = tid; k < CBE; k += 256) {
        int e = base + k;
        if (e < E) {
            int s = load_idx(eidx, isI64, e);
            int d = load_idx(eidx, isI64, E + e);
            if ((unsigned)s < (unsigned)n && (unsigned)d < (unsigned)n)
                atomicAdd(&cnt[d >> CB_BITS], 1);
        }
    }
    __syncthreads();
    {
        int a0 = cnt[2 * tid], a1 = cnt[2 * tid + 1];
        int ps = a0 + a1;
        gbase[tid] = ps;
        __syncthreads();
        int v = ps;
        for (int off = 1; off < 256; off <<= 1) {
            int o = (tid >= off) ? gbase[tid - off] : 0;
            __syncthreads();
            v += o;
            gbase[tid] = v;
            __syncthreads();
        }
        int ex = v - ps;
        pref[2 * tid] = ex;      pref[2 * tid + 1] = ex + a0;
        cur[2 * tid]  = ex;      cur[2 * tid + 1]  = ex + a0;
        if (tid == 255) tot_sh = v;
    }
    __syncthreads();
    const int tot = tot_sh;
    for (int k = tid; k < CBE; k += 256) {
        int e = base + k;
        if (e < E) {
            int s = load_idx(eidx, isI64, e);
            int d = load_idx(eidx, isI64, E + e);
            if ((unsigned)s < (unsigned)n && (unsigned)d < (unsigned)n) {
                int r = atomicAdd(&cur[d >> CB_BITS], 1);
                ebuf[r] = make_uint2((unsigned)s, (unsigned)d);
            }
        }
    }
    __syncthreads();
    for (int i = tid; i < nbins; i += 256) {
        int c = cnt[i];
        gbase[i] = c ? atomicAdd(&coarseCursor[i], c) : 0;
    }
    __syncthreads();
    for (int k = tid; k < tot; k += 256) {
        int lo = 0, hi = nbins;
        while (hi - lo > 1) {
            int mid = (lo + hi) >> 1;
            if (pref[mid] <= k) lo = mid; else hi = mid;
        }
        int g = gbase[lo] + (k - pref[lo]);
        if (g < E) estage[g] = ebuf[k];
    }
}

__global__ __launch_bounds__(256) void fine_bucket_kernel(
    const uint2* __restrict__ estage, const int* __restrict__ coarseOff,
    int* __restrict__ offsets, int* __restrict__ ssrc,
    int E, int n, int nbins) {
    __shared__ int cnt[CB_SIZE];
    __shared__ int pref[CB_SIZE];
    __shared__ int cur[CB_SIZE];
    const int b = blockIdx.x;
    const int tid = threadIdx.x;
    const int beg = coarseOff[b], end = coarseOff[b + 1];
    if (tid < CB_SIZE) cnt[tid] = 0;
    __syncthreads();
    for (int k = beg + tid; k < end; k += 256)
        atomicAdd(&cnt[estage[k].y & (CB_SIZE - 1)], 1);
    __syncthreads();
    {
        int v = (tid < CB_SIZE) ? cnt[tid] : 0;
        if (tid < CB_SIZE) pref[tid] = v;
        __syncthreads();
        for (int off = 1; off < CB_SIZE; off <<= 1) {
            int o = (tid < CB_SIZE && tid >= off) ? pref[tid - off] : 0;
            __syncthreads();
            if (tid < CB_SIZE) { v += o; pref[tid] = v; }
            __syncthreads();
        }
        if (tid < CB_SIZE) {
            int ex = v - cnt[tid];
            cur[tid] = beg + ex;
            int node = (b << CB_BITS) + tid;
            if (node < n) offsets[node] = beg + ex;
        }
    }
    __syncthreads();
    for (int k = beg + tid; k < end; k += 256) {
        uint2 e = estage[k];
        int pos = atomicAdd(&cur[e.y & (CB_SIZE - 1)], 1);
        if (pos < E) ssrc[pos] = (int)e.x;
    }
    if (b == 0 && tid == 0) offsets[n] = coarseOff[nbins];
}

// ================= bf16 conversion + gather =================
__global__ __launch_bounds__(256) void convert_bf16_kernel(
    const float* __restrict__ in, unsigned short* __restrict__ outb,
    long long nelem) {
    long long i = ((long long)blockIdx.x * 256 + threadIdx.x) * 8;
    if (i + 8 > nelem) return;
    float4 f0 = ((const float4*)(in + i))[0];
    float4 f1 = ((const float4*)(in + i))[1];
    uint4 o;
    o.x = pack2(f0.x, f0.y); o.y = pack2(f0.z, f0.w);
    o.z = pack2(f1.x, f1.y); o.w = pack2(f1.z, f1.w);
    *((uint4*)(outb + i)) = o;
}

__device__ __forceinline__ void acc8(float* a, uint4 w) {
    a[0] += __uint_as_float(w.x << 16); a[1] += __uint_as_float(w.x & 0xffff0000u);
    a[2] += __uint_as_float(w.y << 16); a[3] += __uint_as_float(w.y & 0xffff0000u);
    a[4] += __uint_as_float(w.z << 16); a[5] += __uint_as_float(w.z & 0xffff0000u);
    a[6] += __uint_as_float(w.w << 16); a[7] += __uint_as_float(w.w & 0xffff0000u);
}

// thread = (node i, 8-value chunk c in [0,12)); fp32 accumulate, bf16 store.
__global__ __launch_bounds__(256) void gather_agg_bf16_kernel(
    const unsigned short* __restrict__ xb, const int* __restrict__ offsets,
    const int* __restrict__ ssrc, unsigned short* __restrict__ aggb, int n) {
    long long t = (long long)blockIdx.x * 256 + threadIdx.x;
    if (t >= (long long)n * 12) return;
    int i = (int)(t / 12);
    int c = (int)(t % 12);
    int beg = offsets[i], end = offsets[i + 1];
    float accA[8] = {0, 0, 0, 0, 0, 0, 0, 0};
    float accB[8] = {0, 0, 0, 0, 0, 0, 0, 0};
    int j = beg;
    for (; j + 4 <= end; j += 4) {
        int s0 = ssrc[j + 0], s1 = ssrc[j + 1];
        int s2 = ssrc[j + 2], s3 = ssrc[j + 3];
        uint4 w0 = ((const uint4*)(xb + (size_t)s0 * DD))[c];
        uint4 w1 = ((const uint4*)(xb + (size_t)s1 * DD))[c];
        uint4 w2 = ((const uint4*)(xb + (size_t)s2 * DD))[c];
        uint4 w3 = ((const uint4*)(xb + (size_t)s3 * DD))[c];
        acc8(accA, w0); acc8(accB, w1); acc8(accA, w2); acc8(accB, w3);
    }
    for (; j < end; ++j) {
        int s = ssrc[j];
        uint4 w = ((const uint4*)(xb + (size_t)s * DD))[c];
        acc8(accA, w);
    }
    uint4 o;
    o.x = pack2(accA[0] + accB[0], accA[1] + accB[1]);
    o.y = pack2(accA[2] + accB[2], accA[3] + accB[3]);
    o.z = pack2(accA[4] + accB[4], accA[5] + accB[5]);
    o.w = pack2(accA[6] + accB[6], accA[7] + accB[7]);
    *((uint4*)(aggb + (size_t)i * DD + (size_t)c * 8)) = o;
}

// ================= MFMA dual-linear =================
// Pack W = [Wrel; Wroot] (192x96) into 16x16x32 B-fragment layout (bf16):
// frag f = kt*6+nt; lane l: n = nt*16+(l&15), k = kt*32+(l>>4)*8+j, j in [0,8).
__global__ __launch_bounds__(256) void pack_w_kernel(
    const float* __restrict__ Wrel, const float* __restrict__ Wroot,
    uint4* __restrict__ wpack) {
    int t = blockIdx.x * 256 + threadIdx.x;
    if (t >= 36 * 64) return;
    int f = t >> 6, lane = t & 63;
    int kt = f / 6, nt = f % 6;
    int n = nt * 16 + (lane & 15);
    int kbase = kt * 32 + (lane >> 4) * 8;
    float v[8];
    #pragma unroll
    for (int j = 0; j < 8; ++j) {
        int k = kbase + j;
        v[j] = (k < DD) ? Wrel[(size_t)k * DD + n]
                        : Wroot[(size_t)(k - DD) * DD + n];
    }
    uint4 o;
    o.x = pack2(v[0], v[1]); o.y = pack2(v[2], v[3]);
    o.z = pack2(v[4], v[5]); o.w = pack2(v[6], v[7]);
    wpack[t] = o;
}

// out[i,:] = act([Ab_i | Xb_i](192) @ W + bias).  Block = 64 rows x 4 waves.
// Wave pair p = wave>>1 owns N-half (3 ntiles of 16); sub = wave&1 owns
// mtiles {sub, sub+2}. B fragments live entirely in registers (18 frags,
// 72 VGPR) -> zero LDS in the K-loop; A rows fetched once per pair, the
// second pair hits L1/L2 (no cross-block column split => no R5 re-fetch).
__global__ __launch_bounds__(256, 3) void linear_mfma_kernel(
    const unsigned short* __restrict__ Ab, const unsigned short* __restrict__ Xb,
    const uint4* __restrict__ wpack, const float* __restrict__ bias,
    float* __restrict__ outf, unsigned short* __restrict__ outb,
    int n, int do_relu) {
    const int lane = threadIdx.x & 63;
    const int w = threadIdx.x >> 6;
    const int p = w >> 1;            // N-half
    const int sub = w & 1;           // mtile parity
    const int m16 = lane & 15;
    const int quad = lane >> 4;
    const int base = blockIdx.x * 64;

    short8 bfrag[6][3];
    #pragma unroll
    for (int kt = 0; kt < 6; ++kt)
        #pragma unroll
        for (int ntl = 0; ntl < 3; ++ntl) {
            uint4 u = wpack[(kt * 6 + (p * 3 + ntl)) * 64 + lane];
            bfrag[kt][ntl] = *(short8*)&u;
        }

    floatx4 acc[2][3];
    #pragma unroll
    for (int mi = 0; mi < 2; ++mi)
        #pragma unroll
        for (int ntl = 0; ntl < 3; ++ntl)
            acc[mi][ntl] = (floatx4){0.f, 0.f, 0.f, 0.f};

    #pragma unroll
    for (int kt = 0; kt < 6; ++kt) {
        const unsigned short* src = (kt < 3) ? Ab : Xb;
        const int koff = (kt < 3 ? kt : kt - 3) * 32 + quad * 8;
        short8 afrag[2];
        #pragma unroll
        for (int mi = 0; mi < 2; ++mi) {
            int row = base + (sub + mi * 2) * 16 + m16;
            int r = (row < n) ? row : 0;
            afrag[mi] = *(const short8*)(src + (size_t)r * DD + koff);
        }
        #pragma unroll
        for (int ntl = 0; ntl < 3; ++ntl) {
            acc[0][ntl] = __builtin_amdgcn_mfma_f32_16x16x32_bf16(
                afrag[0], bfrag[kt][ntl], acc[0][ntl], 0, 0, 0);
            acc[1][ntl] = __builtin_amdgcn_mfma_f32_16x16x32_bf16(
                afrag[1], bfrag[kt][ntl], acc[1][ntl], 0, 0, 0);
        }
    }

    // C layout: col = lane&15, row-in-tile = quad*4 + reg
    #pragma unroll
    for (int ntl = 0; ntl < 3; ++ntl) {
        const int col = (p * 3 + ntl) * 16 + m16;
        const float bv = bias[col];
        #pragma unroll
        for (int mi = 0; mi < 2; ++mi) {
            #pragma unroll
            for (int reg = 0; reg < 4; ++reg) {
                int row = base + (sub + mi * 2) * 16 + quad * 4 + reg;
                if (row < n) {
                    float v = acc[mi][ntl][reg] + bv;
                    if (do_relu) v = fmaxf(v, 0.f);
                    if (outf) outf[(size_t)row * DD + col] = v;
                    if (outb) outb[(size_t)row * DD + col] =
                        (unsigned short)b16(v);
                }
            }
        }
    }
}

// ================= fallbacks (fp32 path) =================
__global__ __launch_bounds__(256) void scatter_add_kernel(
    const float* __restrict__ feat, const void* __restrict__ eidx,
    const int* __restrict__ flag, float* __restrict__ agg,
    int E, int n) {
    long long t = (long long)blockIdx.x * 256 + threadIdx.x;
    if (t >= (long long)E * 24) return;
    int e = (int)(t / 24);
    int c = (int)(t % 24);
    int isI64 = *flag;
    int s = load_idx(eidx, isI64, e);
    int d = load_idx(eidx, isI64, E + e);
    if ((unsigned)s >= (unsigned)n || (unsigned)d >= (unsigned)n) return;
    const float4 v = ((const float4*)(feat + (size_t)s * DD))[c];
    float* o = agg + (size_t)d * DD + (size_t)c * 4;
    atomicAdd(o + 0, v.x);
    atomicAdd(o + 1, v.y);
    atomicAdd(o + 2, v.z);
    atomicAdd(o + 3, v.w);
}

__global__ __launch_bounds__(256, 4) void linear64_kernel(
    const float* __restrict__ A, const float* __restrict__ X,
    const float* __restrict__ Wrel, const float* __restrict__ bias,
    const float* __restrict__ Wroot, float* __restrict__ out,
    int n, int do_relu) {
    __shared__ float wlds[DD * DD];
    const int lane = threadIdx.x & 63;
    const int q = threadIdx.x >> 6;
    const int j0 = q * 24;
    const int node = blockIdx.x * 64 + lane;
    const bool act = (node < n);
    const int r = act ? node : 0;

    float acc[24];
    {
        const float4* bq = (const float4*)(bias + j0);
        #pragma unroll
        for (int jj = 0; jj < 6; ++jj) {
            float4 b = bq[jj];
            acc[jj*4+0] = b.x; acc[jj*4+1] = b.y;
            acc[jj*4+2] = b.z; acc[jj*4+3] = b.w;
        }
    }
    const float* srcs[2] = {A, X};
    const float* mats[2] = {Wrel, Wroot};
    for (int phase = 0; phase < 2; ++phase) {
        {
            const float4* wg = (const float4*)mats[phase];
            float4* wl = (float4*)wlds;
            #pragma unroll
            for (int i = 0; i < 9; ++i)
                wl[threadIdx.x + i * 256] = wg[threadIdx.x + i * 256];
        }
        __syncthreads();
        const float* row = srcs[phase] + (size_t)r * DD;
        for (int kk = 0; kk < DD; kk += 4) {
            float4 a4 = *(const float4*)(row + kk);
            const float av[4] = {a4.x, a4.y, a4.z, a4.w};
            #pragma unroll
            for (int u = 0; u < 4; ++u) {
                const float4* wrow = (const float4*)(&wlds[(kk + u) * DD + j0]);
                const float ka = av[u];
                #pragma unroll
                for (int jj = 0; jj < 6; ++jj) {
                    float4 ww = wrow[jj];
                    acc[jj*4+0] = fmaf(ka, ww.x, acc[jj*4+0]);
                    acc[jj*4+1] = fmaf(ka, ww.y, acc[jj*4+1]);
                    acc[jj*4+2] = fmaf(ka, ww.z, acc[jj*4+2]);
                    acc[jj*4+3] = fmaf(ka, ww.w, acc[jj*4+3]);
                }
            }
        }
        __syncthreads();
    }
    if (act) {
        float4* o = (float4*)(out + (size_t)node * DD + j0);
        #pragma unroll
        for (int jj = 0; jj < 6; ++jj) {
            float4 v = make_float4(acc[jj*4+0], acc[jj*4+1],
                                   acc[jj*4+2], acc[jj*4+3]);
            if (do_relu) {
                v.x = fmaxf(v.x, 0.f); v.y = fmaxf(v.y, 0.f);
                v.z = fmaxf(v.z, 0.f); v.w = fmaxf(v.w, 0.f);
            }
            o[jj] = v;
        }
    }
}

// alias-safe (X may == out): barrier between reads and stores, block-local rows
__global__ __launch_bounds__(256) void linear_kernel(
    const float* __restrict__ A, const float* __restrict__ X,
    const float* __restrict__ Wrel, const float* __restrict__ bias,
    const float* __restrict__ Wroot, float* __restrict__ out,
    int n, int do_relu) {
    __shared__ float wlds[DD * DD];
    const int lane = threadIdx.x & 63;
    const int q = threadIdx.x >> 6;
    const int j0 = q * 24;
    const int m0 = blockIdx.x * 128 + lane;
    const int m1 = m0 + 64;
    const bool act0 = (m0 < n), act1 = (m1 < n);
    const int r0 = act0 ? m0 : 0;
    const int r1 = act1 ? m1 : 0;

    float acc0[24], acc1[24];
    {
        const float4* bq = (const float4*)(bias + j0);
        #pragma unroll
        for (int jj = 0; jj < 6; ++jj) {
            float4 b = bq[jj];
            acc0[jj*4+0] = b.x; acc0[jj*4+1] = b.y;
            acc0[jj*4+2] = b.z; acc0[jj*4+3] = b.w;
            acc1[jj*4+0] = b.x; acc1[jj*4+1] = b.y;
            acc1[jj*4+2] = b.z; acc1[jj*4+3] = b.w;
        }
    }
    const float* srcs[2] = {A, X};
    const float* mats[2] = {Wrel, Wroot};
    for (int phase = 0; phase < 2; ++phase) {
        {
            const float4* wg = (const float4*)mats[phase];
            float4* wl = (float4*)wlds;
            #pragma unroll
            for (int i = 0; i < 9; ++i)
                wl[threadIdx.x + i * 256] = wg[threadIdx.x + i * 256];
        }
        __syncthreads();
        const float* row0 = srcs[phase] + (size_t)r0 * DD;
        const float* row1 = srcs[phase] + (size_t)r1 * DD;
        for (int kk = 0; kk < DD; kk += 4) {
            float4 a0 = *(const float4*)(row0 + kk);
            float4 a1 = *(const float4*)(row1 + kk);
            const float av0[4] = {a0.x, a0.y, a0.z, a0.w};
            const float av1[4] = {a1.x, a1.y, a1.z, a1.w};
            #pragma unroll
            for (int u = 0; u < 4; ++u) {
                const float4* wrow = (const float4*)(&wlds[(kk + u) * DD + j0]);
                const float k0 = av0[u], k1 = av1[u];
                #pragma unroll
                for (int jj = 0; jj < 6; ++jj) {
                    float4 ww = wrow[jj];
                    acc0[jj*4+0] = fmaf(k0, ww.x, acc0[jj*4+0]);
                    acc0[jj*4+1] = fmaf(k0, ww.y, acc0[jj*4+1]);
                    acc0[jj*4+2] = fmaf(k0, ww.z, acc0[jj*4+2]);
                    acc0[jj*4+3] = fmaf(k0, ww.w, acc0[jj*4+3]);
                    acc1[jj*4+0] = fmaf(k1, ww.x, acc1[jj*4+0]);
                    acc1[jj*4+1] = fmaf(k1, ww.y, acc1[jj*4+1]);
                    acc1[jj*4+2] = fmaf(k1, ww.z, acc1[jj*4+2]);
                    acc1[jj*4+3] = fmaf(k1, ww.w, acc1[jj*4+3]);
                }
            }
        }
        __syncthreads();
    }
    if (act0) {
        float4* o = (float4*)(out + (size_t)m0 * DD + j0);
        #pragma unroll
        for (int jj = 0; jj < 6; ++jj) {
            float4 v = make_float4(acc0[jj*4+0], acc0[jj*4+1],
                                   acc0[jj*4+2], acc0[jj*4+3]);
            if (do_relu) {
                v.x = fmaxf(v.x, 0.f); v.y = fmaxf(v.y, 0.f);
                v.z = fmaxf(v.z, 0.f); v.w = fmaxf(v.w, 0.f);
            }
            o[jj] = v;
        }
    }
    if (act1) {
        float4* o = (float4*)(out + (size_t)m1 * DD + j0);
        #pragma unroll
        for (int jj = 0; jj < 6; ++jj) {
            float4 v = make_float4(acc1[jj*4+0], acc1[jj*4+1],
                                   acc1[jj*4+2], acc1[jj*4+3]);
            if (do_relu) {
                v.x = fmaxf(v.x, 0.f); v.y = fmaxf(v.y, 0.f);
                v.z = fmaxf(v.z, 0.f); v.w = fmaxf(v.w, 0.f);
            }
            o[jj] = v;
        }
    }
}

extern "C" void kernel_launch(void* const* d_in, const int* in_sizes, int n_in,
                              void* d_out, int out_size, void* d_ws, size_t ws_size,
                              hipStream_t stream) {
    const float* x      = (const float*)d_in[0];
    const void*  eidx   = d_in[1];
    const float* W1_rel = (const float*)d_in[2];
    const float* b1     = (const float*)d_in[3];
    const float* W1_root= (const float*)d_in[4];
    const float* W2_rel = (const float*)d_in[5];
    const float* b2     = (const float*)d_in[6];
    const float* W2_root= (const float*)d_in[7];
    float* out = (float*)d_out;

    const int N = in_sizes[0] / DD;   // 50000
    const int E = in_sizes[1] / 2;    // 800000
    const int nbins = (N + CB_SIZE - 1) >> CB_BITS;
    const long long nelem = (long long)N * DD;
    char* base = (char*)d_ws;

    // ---- layout A (MFMA path); only one path runs, so layouts may overlap
    size_t off = 0;
    auto alloc = [&](size_t bytes) {
        size_t o = off; off = (off + bytes + 255) & ~(size_t)255; return base + o; };
    int*   flag       = (int*)  alloc(256);           // shared: first in BOTH layouts
    int*   offsets    = (int*)  alloc((size_t)(N + 1) * 4);
    int*   ssrc       = (int*)  alloc((size_t)E * 4);
    int*   coarseHist = (int*)  alloc(CB_MAXBINS * 4);
    int*   coarseOff  = (int*)  alloc((CB_MAXBINS + 1) * 4);
    int*   coarseCur  = (int*)  alloc((CB_MAXBINS + 1) * 4);
    uint2* estage     = (uint2*)alloc((size_t)E * 8);
    unsigned short* xb   = (unsigned short*)alloc((size_t)nelem * 2);
    unsigned short* hb   = (unsigned short*)alloc((size_t)nelem * 2);
    unsigned short* aggb = (unsigned short*)alloc((size_t)nelem * 2);
    uint4* wpack1     = (uint4*)alloc(36 * 64 * 16);
    uint4* wpack2     = (uint4*)alloc(36 * 64 * 16);
    const bool mfma_ok = (off <= ws_size) && (nbins <= CB_MAXBINS);

    // ---- layout B (fp32 fallback): reuse space after flag
    size_t offB = 256;
    auto allocB = [&](size_t bytes) {
        size_t o = offB; offB = (offB + bytes + 255) & ~(size_t)255; return base + o; };
    float* agg = (float*)allocB((size_t)nelem * 4);
    const bool fb_ok = (offB <= ws_size);

    const int lin64_blocks = (N + 63) / 64;
    const int mfma_blocks = (N + 63) / 64;
    const int edge_blocks4 = (E + 1023) / 1024;

    detect_idx_kernel<<<1, 256, 0, stream>>>(
        (const unsigned long long*)eidx, flag, (unsigned long long)N);

    if (mfma_ok) {
        // CSR build
        hipMemsetAsync(coarseHist, 0, CB_MAXBINS * 4, stream);
        hist_coarse_kernel<<<edge_blocks4, 256, 0, stream>>>(
            eidx, flag, coarseHist, E, N);
        coarse_scan_kernel<<<1, 256, 0, stream>>>(
            coarseHist, coarseOff, coarseCur, nbins);
        coarse_bin_kernel<<<(E + CBE - 1) / CBE, 256, 0, stream>>>(
            eidx, flag, coarseCur, estage, E, N, nbins);
        fine_bucket_kernel<<<nbins, 256, 0, stream>>>(
            estage, coarseOff, offsets, ssrc, E, N, nbins);

        // weights + x to bf16
        pack_w_kernel<<<9, 256, 0, stream>>>(W1_rel, W1_root, wpack1);
        pack_w_kernel<<<9, 256, 0, stream>>>(W2_rel, W2_root, wpack2);
        const int conv_blocks = (int)((nelem / 8 + 255) / 256);
        convert_bf16_kernel<<<conv_blocks, 256, 0, stream>>>(x, xb, nelem);

        const int gb = (int)(((long long)N * 12 + 255) / 256);
        // Layer 1: h (bf16) only
        gather_agg_bf16_kernel<<<gb, 256, 0, stream>>>(xb, offsets, ssrc, aggb, N);
        linear_mfma_kernel<<<mfma_blocks, 256, 0, stream>>>(
            aggb, xb, wpack1, b1, (float*)nullptr, hb, N, 1);
        // Layer 2: fp32 out
        gather_agg_bf16_kernel<<<gb, 256, 0, stream>>>(hb, offsets, ssrc, aggb, N);
        linear_mfma_kernel<<<mfma_blocks, 256, 0, stream>>>(
            aggb, hb, wpack2, b2, out, (unsigned short*)nullptr, N, 0);
    } else if (fb_ok) {
        const int scatter_blocks = (int)(((long long)E * 24 + 255) / 256);
        hipMemsetAsync(agg, 0, (size_t)nelem * 4, stream);
        scatter_add_kernel<<<scatter_blocks, 256, 0, stream>>>(x, eidx, flag, agg, E, N);
        linear64_kernel<<<lin64_blocks, 256, 0, stream>>>(
            agg, x, W1_rel, b1, W1_root, out, N, 1);
        hipMemsetAsync(agg, 0, (size_t)nelem * 4, stream);
        scatter_add_kernel<<<scatter_blocks, 256, 0, stream>>>(out, eidx, flag, agg, E, N);
        linear_kernel<<<(N + 127) / 128, 256, 0, stream>>>(
            agg, out, W2_rel, b2, W2_root, out, N, 0);
    }
}